// Round 9
// baseline (538.874 us; speedup 1.0000x reference)
//
#include <hip/hip_runtime.h>
#include <hip/hip_bf16.h>

typedef __hip_bfloat16 bf16;
typedef __bf16 bf8 __attribute__((ext_vector_type(8)));
typedef float  f4  __attribute__((ext_vector_type(4)));

#define N_ATOMS 25000
#define NE      800000
#define NEA     300000
#define NT      1600000
#define APB     64
#define NBUK    ((N_ATOMS + APB - 1) / APB)   // 391

#define DIN0  376
#define DIN1  616
#define DINP0 384
#define DINP1 640

#define EBLK ((NE + 4095) / 4096)   // 196
#define TBLK ((NT + 4095) / 4096)   // 391

#define NFRAG0 ((DINP0 / 32) * 16 * 64)   // 12288
#define NFRAG1 ((DINP1 / 32) * 16 * 64)   // 20480
#define NFRAGS (8 * 6 * 64)               // 3072
#define WBLK   ((NFRAG0 + NFRAG1 + NFRAGS + 255) / 256)   // 140

#define S0BLK2 ((N_ATOMS * 120 + 511) / 512)   // 5860
#define DABLK2 ((NEA + 1 + 511) / 512)         // 587

#define SCH ((N_ATOMS + 511) / 512)   // 49

#define MIBLK ((N_ATOMS + 1) / 2)   // 12500

__device__ __forceinline__ float tssr2f(float x) {
    float ax = fabsf(x);
    return (ax <= 1.f) ? x : copysignf(2.f * __builtin_sqrtf(ax) - 1.f, x);
}

__device__ __forceinline__ unsigned short f2bf_rn(float v) {
    unsigned int b = __float_as_uint(v);
    b += 0x7FFF + ((b >> 16) & 1);
    return (unsigned short)(b >> 16);
}
__device__ __forceinline__ float bf2f(unsigned short u) {
    return __uint_as_float(((unsigned int)u) << 16);
}

// ------------------------------------------------------------------
// k_wc (fused): blocks [0,WBLK) = W->bf16 fragment prep (3 matrices);
// rest = per-ATOM counts via global atomics (edges -> acnt, triplets
// -> tcnt). Per-atom counts enable PADDED offsets (multiples of 8).
// ------------------------------------------------------------------
__device__ __forceinline__ void wprep_one(const float* __restrict__ W, bf8* __restrict__ Wf,
                                          int K, int N, int ntiles, int f) {
    int lane = f & 63;
    int ft = f >> 6;
    int tile = ft % ntiles;
    int chunk = ft / ntiles;
    int n = tile * 16 + (lane & 15);
    int kb = chunk * 32 + (lane >> 4) * 8;
    bf8 v;
#pragma unroll
    for (int j = 0; j < 8; j++) {
        int k = kb + j;
        v[j] = (__bf16)((k < K) ? W[k * N + n] : 0.f);
    }
    Wf[f] = v;
}

__global__ __launch_bounds__(256) void k_wc(const float* __restrict__ W0, bf8* __restrict__ Wf0,
                                            const float* __restrict__ W1, bf8* __restrict__ Wf1,
                                            const float* __restrict__ WS, bf8* __restrict__ WfS,
                                            const int* __restrict__ esrc, const int* __restrict__ cat,
                                            int* __restrict__ acnt, int* __restrict__ tcnt) {
    int bid = blockIdx.x;
    if (bid < WBLK) {
        int f = bid * 256 + threadIdx.x;
        if (f < NFRAG0) {
            wprep_one(W0, Wf0, DIN0, 256, 16, f);
        } else if (f < NFRAG0 + NFRAG1) {
            wprep_one(W1, Wf1, DIN1, 256, 16, f - NFRAG0);
        } else if (f < NFRAG0 + NFRAG1 + NFRAGS) {
            wprep_one(WS, WfS, 256, 96, 6, f - NFRAG0 - NFRAG1);
        }
        return;
    }
    bid -= WBLK;
    bool isE = bid < EBLK;
    const int* key = isE ? esrc : cat;
    int n = isE ? NE : NT;
    int* cp = isE ? acnt : tcnt;
    int base = (isE ? bid : bid - EBLK) * 4096;
    int t = threadIdx.x;
#pragma unroll
    for (int k = 0; k < 16; k++) {
        int idx = base + k * 256 + t;
        if (idx < n) atomicAdd(&cp[key[idx]], 1);
    }
}

// ------------------------------------------------------------------
// k_scanA: per-atom PADDED prefix sums (pad each atom's count to a
// multiple of 8). Block 0 = edges, block 1 = triplets. Also emits the
// per-bucket staging bases gce/gct (= padded offset of bucket's first
// atom) used by binning.
// ------------------------------------------------------------------
__global__ __launch_bounds__(512) void k_scanA(const int* __restrict__ acnt, int* __restrict__ epoff,
                                               int* __restrict__ gce,
                                               const int* __restrict__ tcnt, int* __restrict__ tpoff,
                                               int* __restrict__ gct) {
    const int* cnt = blockIdx.x ? tcnt : acnt;
    int* off = blockIdx.x ? tpoff : epoff;
    int* gc  = blockIdx.x ? gct : gce;
    __shared__ int sh[512];
    int t = threadIdx.x;
    int i0 = t * SCH, i1 = min(i0 + SCH, N_ATOMS);
    int s = 0;
    for (int i = i0; i < i1; i++) s += (cnt[i] + 7) & ~7;
    sh[t] = s;
    __syncthreads();
    for (int d = 1; d < 512; d <<= 1) {
        int a = (t >= d) ? sh[t - d] : 0;
        __syncthreads();
        sh[t] += a;
        __syncthreads();
    }
    int run = sh[t] - s;
    for (int i = i0; i < i1; i++) { off[i] = run; run += (cnt[i] + 7) & ~7; }
    if (t == 0) off[N_ATOMS] = sh[511];
    __syncthreads();
    for (int b = t; b < NBUK; b += 512) gc[b] = off[b * APB];
}

// ------------------------------------------------------------------
// k_bpre (fused): blocks [0, EBLK+TBLK) = phase-A binning (staging
// into coarse buckets at PADDED bases); then layer-0 species/si fill
// (ei0 bf16); then da for BOTH layers (+ zero sentinel row at NEA so
// triplet pads contribute exactly 0).
// ------------------------------------------------------------------
__global__ __launch_bounds__(512) void k_bpre(const float* __restrict__ eA,
                                              const float* __restrict__ eB,
                                              const int* __restrict__ eC,
                                              const int* __restrict__ ekey,
                                              int* __restrict__ egcur,
                                              float4* __restrict__ ebuk,
                                              const float* __restrict__ tA,
                                              const int* __restrict__ tB,
                                              const int* __restrict__ tC,
                                              const int* __restrict__ tkey,
                                              int* __restrict__ tgcur,
                                              float4* __restrict__ tbuk,
                                              const int* __restrict__ sp,
                                              const float* __restrict__ table,
                                              const float* __restrict__ Wsi,
                                              unsigned short* __restrict__ ei0,
                                              float* __restrict__ sd,
                                              const float* __restrict__ dist,
                                              const float* __restrict__ sw2,
                                              const float* __restrict__ Wda0,
                                              const float* __restrict__ Wda1,
                                              unsigned short* __restrict__ dah0,
                                              unsigned short* __restrict__ dah1) {
    int bid = blockIdx.x;
    int t = threadIdx.x;
    if (bid < EBLK + TBLK) {
        __shared__ int cnt[NBUK];
        __shared__ int rbase[NBUK];
        for (int b = t; b < NBUK; b += 512) cnt[b] = 0;
        __syncthreads();
        bool isE = bid < EBLK;
        const int* key = isE ? ekey : tkey;
        int n = isE ? NE : NT;
        int* gcur = isE ? egcur : tgcur;
        float4* buk = isE ? ebuk : tbuk;
        int base = (isE ? bid : (bid - EBLK)) * 4096;
        float4 pay[8];
        int bk[8], off[8];
#pragma unroll
        for (int k = 0; k < 8; k++) {
            int idx = base + k * 512 + t;
            bk[k] = -1;
            if (idx < n) {
                float4 p;
                if (isE) {
                    p.x = eA[idx];
                    p.y = eB[idx];
                    p.z = __int_as_float(eC[idx]);
                } else {
                    p.x = __cosf(tA[idx]);
                    p.y = __int_as_float(tB[idx]);
                    p.z = __int_as_float(tC[idx]);
                }
                int ky = key[idx];
                p.w = __int_as_float(ky);
                pay[k] = p;
                bk[k] = ky >> 6;
                off[k] = atomicAdd(&cnt[bk[k]], 1);
            }
        }
        __syncthreads();
        for (int b = t; b < NBUK; b += 512)
            if (cnt[b]) rbase[b] = atomicAdd(&gcur[b], cnt[b]);
        __syncthreads();
#pragma unroll
        for (int k = 0; k < 8; k++)
            if (bk[k] >= 0) buk[rbase[bk[k]] + off[k]] = pay[k];
    } else if (bid < EBLK + TBLK + S0BLK2) {
        int idx = (bid - EBLK - TBLK) * 512 + t;
        if (idx >= N_ATOMS * 120) return;
        int i = idx / 120;
        int c = idx - i * 120;
        if (c >= 112) {
            ei0[(size_t)i * DINP0 + 376 + (c - 112)] = 0;
            return;
        }
        int s = sp[i];
        if (c < 16) {
            ei0[(size_t)i * DINP0 + c] = f2bf_rn(table[s * 16 + c]);
        } else {
            int cc = c - 16;
            float acc = 0.f;
#pragma unroll
            for (int k = 0; k < 16; k++)
                acc += table[s * 16 + k] * Wsi[k * 96 + cc];
            if (cc < 64) ei0[(size_t)i * DINP0 + 16 + cc] = f2bf_rn(acc);
            else         sd[i * 32 + cc - 64]             = acc;
        }
    } else {
        int e = (bid - EBLK - TBLK - S0BLK2) * 512 + t;
        if (e > NEA) return;
        if (e == NEA) {   // sentinel row: triplet pads index here -> dij = 0
            uint4 z = make_uint4(0, 0, 0, 0);
            *(uint4*)&dah0[(size_t)e * 8] = z;
            *(uint4*)&dah1[(size_t)e * 8] = z;
            return;
        }
        float d = dist[e];
        float s = sw2[e];
        float rb[8];
#pragma unroll
        for (int n = 0; n < 8; n++)
            rb[n] = 0.7559289460f * __sinf((n + 1) * 0.8975979010f * d) / d * s;
        unsigned short h0[8], h1[8];
#pragma unroll
        for (int c = 0; c < 8; c++) {
            float a0 = 0.f, a1 = 0.f;
#pragma unroll
            for (int n = 0; n < 8; n++) {
                a0 += rb[n] * Wda0[n * 8 + c];
                a1 += rb[n] * Wda1[n * 8 + c];
            }
            h0[c] = f2bf_rn(a0);
            h1[c] = f2bf_rn(a1);
        }
        *(uint4*)&dah0[e * 8] = *(uint4*)h0;
        *(uint4*)&dah1[e * 8] = *(uint4*)h1;
    }
}

// ------------------------------------------------------------------
// k_binB2: one workgroup per bucket; blocks [0,NBUK) edges, rest
// triplets. Scatters to PADDED per-atom slots. EDGES: rb[8] written
// GROUP-TRANSPOSED ([n][j] within each 8-edge group) so k_seg reads
// rb with two broadcast float4 loads (no shfl). Pad slots zero-filled
// (rb=0 / sentinel triplets) so k_seg needs NO masks at all.
// ------------------------------------------------------------------
__global__ __launch_bounds__(256) void k_binB2(const int* __restrict__ epoff,
                                               const int* __restrict__ acnt,
                                               const int* __restrict__ gce,
                                               const float4* __restrict__ ebuk,
                                               float* __restrict__ erb,
                                               int* __restrict__ edi,
                                               const int* __restrict__ tpoff,
                                               const int* __restrict__ tcnt,
                                               const int* __restrict__ gct,
                                               const float4* __restrict__ tbuk,
                                               float4* __restrict__ tpay) {
    bool isE = blockIdx.x < NBUK;
    int b = isE ? blockIdx.x : (blockIdx.x - NBUK);
    const int* off  = isE ? epoff : tpoff;
    const int* cntA = isE ? acnt : tcnt;
    const int* gfin = isE ? gce : gct;
    const float4* buk = isE ? ebuk : tbuk;
    int lo = b * APB;
    int hi = min(lo + APB, N_ATOMS);
    __shared__ int abase[APB];
    __shared__ int cur[APB];
    int t = threadIdx.x;
    if (t < hi - lo) {
        int base = off[lo + t];
        int pe   = off[lo + t + 1];
        int c    = cntA[lo + t];
        abase[t] = base;
        cur[t]   = base;
        if (isE) {
            for (int s = base + c; s < pe; s++) {
                edi[s] = 0;
                int pos = s - base;
                float* dz = erb + ((size_t)base + (pos & ~7)) * 8 + (pos & 7);
#pragma unroll
                for (int nn = 0; nn < 8; nn++) dz[nn * 8] = 0.f;
            }
        } else {
            float4 pz = make_float4(0.f, __int_as_float(NEA), __int_as_float(NEA), 0.f);
            for (int s = base + c; s < pe; s++) tpay[s] = pz;
        }
    }
    __syncthreads();
    int pstart = off[lo];
    int pend = gfin[b];
    for (int p = pstart + t; p < pend; p += 256) {
        float4 pay = buk[p];
        int a = __float_as_int(pay.w);
        int k = a - lo;
        int slot = atomicAdd(&cur[k], 1);
        if (isE) {
            float d = pay.x, s2 = pay.y;
            float q = 0.6324555320f * s2 / d;
            int pos = slot - abase[k];
            float* dst = erb + ((size_t)abase[k] + (pos & ~7)) * 8 + (pos & 7);
#pragma unroll
            for (int nn = 0; nn < 8; nn++)
                dst[nn * 8] = q * __sinf((nn + 1) * 0.6283185307f * d);
            edi[slot] = __float_as_int(pay.z);
        } else {
            tpay[slot] = pay;
        }
    }
}

// ------------------------------------------------------------------
// layer 1 s: MFMA GEMM 25000x96 (ei1 bf16: A-staging is raw 16B copy)
// ------------------------------------------------------------------
__global__ __launch_bounds__(256) void k_s1(const unsigned short* __restrict__ ei1,
                                            const bf8* __restrict__ Wf,
                                            unsigned short* __restrict__ ei1o,
                                            float* __restrict__ sd) {
    __shared__ __align__(16) __bf16 Asg[4][64][8];
    int t = threadIdx.x;
    int w = t >> 6, lane = t & 63;
    int a0 = blockIdx.x * 64;

    int satom = a0 + (t >> 2);
    int k8 = (t & 3) * 8;
    const unsigned short* arow = &ei1[(size_t)satom * DINP1 + k8];
    bool aok = satom < N_ATOMS;
    int dw = (t >> 2) >> 4;
    int dl = ((t >> 2) & 15) | ((t & 3) << 4);
    __bf16* adst = &Asg[dw][dl][0];

    f4 acc[6];
#pragma unroll
    for (int j = 0; j < 6; j++) {
        f4 z = {0.f, 0.f, 0.f, 0.f};
        acc[j] = z;
    }

    for (int ch = 0; ch < 8; ch++) {
        uint4 v = make_uint4(0, 0, 0, 0);
        if (aok) v = *(const uint4*)(arow + ch * 32);
        __syncthreads();
        *(uint4*)adst = v;
        __syncthreads();
        bf8 afr = *(const bf8*)&Asg[w][lane][0];
        const bf8* wp = &Wf[(ch * 6) * 64 + lane];
#pragma unroll
        for (int tn = 0; tn < 6; tn++) {
            bf8 b = wp[tn * 64];
            acc[tn] = __builtin_amdgcn_mfma_f32_16x16x32_bf16(afr, b, acc[tn], 0, 0, 0);
        }
    }

    int nlo = lane & 15, q = lane >> 4;
#pragma unroll
    for (int r = 0; r < 4; r++) {
        int atom = a0 + w * 16 + q * 4 + r;
        if (atom < N_ATOMS) {
#pragma unroll
            for (int tn = 0; tn < 6; tn++) {
                int col = tn * 16 + nlo;
                float v = acc[tn][r];
                if (col < 64) ei1o[(size_t)atom * DINP1 + 256 + col] = f2bf_rn(v);
                else          sd[atom * 32 + col - 64] = v;
            }
        }
    }
    for (int z = t; z < 64 * 24; z += 256) {
        int za = a0 + z / 24;
        if (za < N_ATOMS) ei1o[(size_t)za * DINP1 + 616 + z % 24] = 0;
    }
}

// ------------------------------------------------------------------
// ami window helper (MASKLESS: pads are sentinel triplets with cos=0
// and dah-row 0 -> contribute exactly 0). 1-deep dah prefetch.
// ------------------------------------------------------------------
__device__ __forceinline__ void ami_win(const float4 twA, const unsigned short* __restrict__ dah,
                                        int gmax, int jj, int c,
                                        float& a0, float& a1, float& a2, float& a3, float& a4) {
    float sc = 0.f; unsigned short dA = 0, dB = 0;
    {
        sc = __shfl(twA.x, jj, 64);
        int ea = __float_as_int(__shfl(twA.y, jj, 64));
        int eb = __float_as_int(__shfl(twA.z, jj, 64));
        dA = dah[ea * 8 + c];
        dB = dah[eb * 8 + c];
    }
    for (int g = 0; g < gmax; g++) {
        float scN = 0.f; unsigned short dAN = 0, dBN = 0;
        if (g + 1 < gmax) {
            int sl = (g + 1) * 8 + jj;
            scN = __shfl(twA.x, sl, 64);
            int ea = __float_as_int(__shfl(twA.y, sl, 64));
            int eb = __float_as_int(__shfl(twA.z, sl, 64));
            dAN = dah[ea * 8 + c];
            dBN = dah[eb * 8 + c];
        }
        float dij = bf2f(dA) * bf2f(dB);
        float c1 = sc;
        float c2 = __builtin_fmaf(2.f * c1, c1, -1.f);
        float c3 = __builtin_fmaf(2.f * c1, c2, -c1);
        float c4 = __builtin_fmaf(2.f * c1, c3, -c2);
        a0 += dij;
        a1 = __builtin_fmaf(c1, dij, a1);
        a2 = __builtin_fmaf(c2, dij, a2);
        a3 = __builtin_fmaf(c3, dij, a3);
        a4 = __builtin_fmaf(c4, dij, a4);
        if (g + 1 < gmax) { sc = scN; dA = dAN; dB = dBN; }
    }
}

// ------------------------------------------------------------------
// k_seg: 2 atoms/block, 2 waves/atom (r6-proven; r7's 4-wave split
// regressed on fixed overhead). ami blocks first (LPT). PADDED
// offsets + group-transposed erb: the mi inner loop has NO shfl for
// rb (two broadcast float4 loads) and NO masks anywhere (pads = 0).
// ------------------------------------------------------------------
__global__ __launch_bounds__(256) void k_seg(const int* __restrict__ eoff,
                                             const float* __restrict__ erb,
                                             const int* __restrict__ edi,
                                             const float* __restrict__ sd,
                                             unsigned short* __restrict__ mo, int mstride,
                                             const int* __restrict__ toff,
                                             const float4* __restrict__ tpay,
                                             const unsigned short* __restrict__ dah,
                                             unsigned short* __restrict__ ao, int astride) {
    __shared__ float4 smi[2][64];
    __shared__ float  sam[2][5][8];
    int t = threadIdx.x;
    int wv = t >> 6, l = t & 63;
    int slot = wv >> 1;
    int p    = wv & 1;

    if ((int)blockIdx.x < MIBLK) {
        // ---------------- ami ----------------
        int i = blockIdx.x * 2 + slot;
        bool valid = (i < N_ATOMS);
        int pbeg = 0, pend = 0;
        if (valid) { pbeg = toff[i]; pend = toff[i + 1]; }
        int pcnt = pend - pbeg;   // multiple of 8
        int jj = l >> 3, c = l & 7;
        float a0 = 0.f, a1 = 0.f, a2 = 0.f, a3 = 0.f, a4 = 0.f;

        if (pcnt > 0) {
            int nG = pcnt >> 3;
            if (pcnt <= 128) {
                int h0 = (nG + 1) >> 1;
                int gb = p ? h0 : 0;
                int myg = p ? (nG - h0) : h0;
                if (myg > 0) {
                    int tb = gb * 8;
                    float4 twA = tpay[pbeg + tb + min(l, myg * 8 - 1)];
                    ami_win(twA, dah, myg, jj, c, a0, a1, a2, a3, a4);
                }
            } else {
                int nW = (pcnt + 63) >> 6;
                for (int W = p; W < nW; W += 2) {
                    int wbase = W * 64;
                    int rem = pcnt - wbase;
                    int lim = min(rem, 64);
                    float4 twA = tpay[pbeg + wbase + min(l, rem - 1)];
                    ami_win(twA, dah, lim >> 3, jj, c, a0, a1, a2, a3, a4);
                }
            }
        }

        // reduce over jj within wave (lanes l, l^8, l^16, l^32)
#pragma unroll
        for (int msk = 8; msk <= 32; msk <<= 1) {
            a0 += __shfl_xor(a0, msk, 64);
            a1 += __shfl_xor(a1, msk, 64);
            a2 += __shfl_xor(a2, msk, 64);
            a3 += __shfl_xor(a3, msk, 64);
            a4 += __shfl_xor(a4, msk, 64);
        }
        if (p == 1 && l < 8) {
            sam[slot][0][l] = a0; sam[slot][1][l] = a1; sam[slot][2][l] = a2;
            sam[slot][3][l] = a3; sam[slot][4][l] = a4;
        }
        __syncthreads();
        if (valid && p == 0 && l < 8) {
            a0 += sam[slot][0][l]; a1 += sam[slot][1][l]; a2 += sam[slot][2][l];
            a3 += sam[slot][3][l]; a4 += sam[slot][4][l];
            unsigned short* o = &ao[(size_t)i * astride + c];
            o[0]  = f2bf_rn(a0);
            o[8]  = f2bf_rn(a1);
            o[16] = f2bf_rn(a2);
            o[24] = f2bf_rn(a3);
            o[32] = f2bf_rn(a4);
        }
    } else {
        // ---------------- mi ----------------
        int i = ((int)blockIdx.x - MIBLK) * 2 + slot;
        bool valid = (i < N_ATOMS);
        int pbeg = 0, pend = 0;
        if (valid) { pbeg = eoff[i]; pend = eoff[i + 1]; }
        int pcnt = pend - pbeg;   // multiple of 8
        int n = l >> 3, cb = (l & 7) * 4;
        float4 acc = make_float4(0.f, 0.f, 0.f, 0.f);

        if (pcnt > 0) {
            int nG = pcnt >> 3;
            int h0 = (nG + 1) >> 1;
            int gbeg = p ? h0 : 0;
            int gend = p ? nG : h0;
            if (pcnt <= 64) {
                int eWin = edi[pbeg + min(l, pcnt - 1)];
                for (int g = gbeg; g < gend; g++) {
                    const float* rp = erb + ((size_t)pbeg + g * 8) * 8 + n * 8;
                    f4 rA = *(const f4*)rp;
                    f4 rB = *(const f4*)(rp + 4);
                    float4 v[8];
#pragma unroll
                    for (int j = 0; j < 8; j++) {
                        int eid = __shfl(eWin, g * 8 + j, 64);
                        v[j] = *(const float4*)&sd[eid * 32 + cb];
                    }
#pragma unroll
                    for (int j = 0; j < 8; j++) {
                        float rbj = (j < 4) ? rA[j] : rB[j - 4];
                        acc.x += rbj * v[j].x; acc.y += rbj * v[j].y;
                        acc.z += rbj * v[j].z; acc.w += rbj * v[j].w;
                    }
                }
            } else {
                const int* dp = edi + pbeg;
                for (int g = gbeg; g < gend; g++) {
                    const float* rp = erb + ((size_t)pbeg + g * 8) * 8 + n * 8;
                    f4 rA = *(const f4*)rp;
                    f4 rB = *(const f4*)(rp + 4);
                    float4 v[8];
#pragma unroll
                    for (int j = 0; j < 8; j++) {
                        int eid = dp[g * 8 + j];
                        v[j] = *(const float4*)&sd[eid * 32 + cb];
                    }
#pragma unroll
                    for (int j = 0; j < 8; j++) {
                        float rbj = (j < 4) ? rA[j] : rB[j - 4];
                        acc.x += rbj * v[j].x; acc.y += rbj * v[j].y;
                        acc.z += rbj * v[j].z; acc.w += rbj * v[j].w;
                    }
                }
            }
        }

        if (p == 1) smi[slot][l] = acc;
        __syncthreads();
        if (valid && p == 0) {
            float4 o = smi[slot][l];
            acc.x += o.x; acc.y += o.y; acc.z += o.z; acc.w += o.w;
            ushort4 pk = make_ushort4(f2bf_rn(acc.x), f2bf_rn(acc.y),
                                      f2bf_rn(acc.z), f2bf_rn(acc.w));
            *(ushort4*)&mo[(size_t)i * mstride + l * 4] = pk;   // n*32+cb == l*4
        }
    }
}

// ------------------------------------------------------------------
// MFMA GEMM: dxi = tssr2(ei @ W + b). ei bf16 (raw 8B A-staging).
// LAYER 0 writes bf16 ei1; LAYER 1 writes fp32 out with bf16 skip.
// ------------------------------------------------------------------
template <int LAYER>
__global__ __launch_bounds__(256) void k_gemm(const unsigned short* __restrict__ ei,
                                              const bf8* __restrict__ Wf,
                                              const float* __restrict__ bias,
                                              const unsigned short* __restrict__ skip,
                                              float* __restrict__ outf,
                                              unsigned short* __restrict__ outb) {
    constexpr int DINP = (LAYER == 0) ? DINP0 : DINP1;
    constexpr int NCH = DINP / 32;
    __shared__ __align__(16) __bf16 Asg[2][64][8];
    int t = threadIdx.x;
    int w = t >> 6, lane = t & 63;
    int a0 = blockIdx.x * 32;

    int f  = t * 4;
    int tA = f >> 9;
    int al = (f >> 3) & 63;
    int j0 = f & 7;
    int sm = al & 15, sq = al >> 4;
    int ga = a0 + tA * 16 + sm;
    const unsigned short* arow = &ei[(size_t)ga * DINP + sq * 8 + j0];
    __bf16* adst = &Asg[0][0][0] + f;
    bool aok = (ga < N_ATOMS);

    f4 acc[2][4];
#pragma unroll
    for (int i = 0; i < 2; i++)
#pragma unroll
        for (int j = 0; j < 4; j++) {
            f4 z = {0.f, 0.f, 0.f, 0.f};
            acc[i][j] = z;
        }

    for (int ch = 0; ch < NCH; ch++) {
        uint2 v = make_uint2(0, 0);
        if (aok) v = *(const uint2*)(arow + ch * 32);
        __syncthreads();
        *(uint2*)adst = v;
        __syncthreads();
        bf8 afr0 = *(const bf8*)&Asg[0][lane][0];
        bf8 afr1 = *(const bf8*)&Asg[1][lane][0];
        const bf8* wp = &Wf[(ch * 16 + w * 4) * 64 + lane];
#pragma unroll
        for (int tn = 0; tn < 4; tn++) {
            bf8 b = wp[tn * 64];
            acc[0][tn] = __builtin_amdgcn_mfma_f32_16x16x32_bf16(afr0, b, acc[0][tn], 0, 0, 0);
            acc[1][tn] = __builtin_amdgcn_mfma_f32_16x16x32_bf16(afr1, b, acc[1][tn], 0, 0, 0);
        }
    }

    int nlo = lane & 15, q = lane >> 4;
#pragma unroll
    for (int tA2 = 0; tA2 < 2; tA2++) {
#pragma unroll
        for (int r = 0; r < 4; r++) {
            int atom = a0 + tA2 * 16 + q * 4 + r;
            if (atom < N_ATOMS) {
#pragma unroll
                for (int tn = 0; tn < 4; tn++) {
                    int col = w * 64 + tn * 16 + nlo;
                    float vv = tssr2f(acc[tA2][tn][r] + bias[col]);
                    if (LAYER == 0) {
                        outb[(size_t)atom * DINP1 + col] = f2bf_rn(vv);
                    } else {
                        outf[(size_t)atom * 256 + col] =
                            vv + bf2f(skip[(size_t)atom * DINP1 + col]);
                    }
                }
            }
        }
    }
}

// ------------------------------------------------------------------
extern "C" void kernel_launch(void* const* d_in, const int* in_sizes, int n_in,
                              void* d_out, int out_size, void* d_ws, size_t ws_size,
                              hipStream_t stream) {
    const int*   species     = (const int*)d_in[0];
    const int*   edge_src    = (const int*)d_in[1];
    const int*   edge_dst    = (const int*)d_in[2];
    const float* distances   = (const float*)d_in[3];
    const float* sw          = (const float*)d_in[4];
    const float* angles      = (const float*)d_in[5];
    const int*   angle_src   = (const int*)d_in[6];
    const int*   angle_dst   = (const int*)d_in[7];
    const int*   central     = (const int*)d_in[8];
    const float* dist_a      = (const float*)d_in[9];
    const float* sw_a        = (const float*)d_in[10];
    const float* table       = (const float*)d_in[11];
    const float* W_si0       = (const float*)d_in[12];
    const float* W_si1       = (const float*)d_in[13];
    const float* W_da0       = (const float*)d_in[14];
    const float* W_da1       = (const float*)d_in[15];
    const float* W_mix0      = (const float*)d_in[16];
    const float* b_mix0      = (const float*)d_in[17];
    const float* W_mix1      = (const float*)d_in[18];
    const float* b_mix1      = (const float*)d_in[19];
    float* out = (float*)d_out;

    char* p = (char*)d_ws;
    auto alloc = [&](size_t bytes) {
        char* r = p;
        p += (bytes + 255) & ~(size_t)255;
        return (void*)r;
    };
    unsigned short* ei0 = (unsigned short*)alloc((size_t)N_ATOMS * DINP0 * 2);
    unsigned short* ei1 = (unsigned short*)alloc((size_t)N_ATOMS * DINP1 * 2);
    float*  sd   = (float*)alloc((size_t)N_ATOMS * 32 * 4);
    unsigned short* dah0 = (unsigned short*)alloc((size_t)(NEA + 1) * 8 * 2);
    unsigned short* dah1 = (unsigned short*)alloc((size_t)(NEA + 1) * 8 * 2);
    float*  erbf = (float*)alloc((size_t)(NE + 8 * N_ATOMS) * 8 * 4);
    int*    edi  = (int*)alloc((size_t)(NE + 8 * N_ATOMS) * 4);
    float4* tpay = (float4*)alloc((size_t)(NT + 8 * N_ATOMS) * 16);
    float4* ebuk = (float4*)alloc((size_t)(NE + 8 * N_ATOMS) * 16);
    bf8*    Wf0  = (bf8*)alloc((size_t)NFRAG0 * 16);
    bf8*    Wf1  = (bf8*)alloc((size_t)NFRAG1 * 16);
    bf8*    WfS1 = (bf8*)alloc((size_t)NFRAGS * 16);
    int* epoff  = (int*)alloc((size_t)(N_ATOMS + 1) * 4);
    int* tpoff  = (int*)alloc((size_t)(N_ATOMS + 1) * 4);
    int* cnts   = (int*)alloc((size_t)2 * N_ATOMS * 4);   // acnt | tcnt
    int* gce    = (int*)alloc((size_t)NBUK * 4);
    int* gct    = (int*)alloc((size_t)NBUK * 4);
    (void)ws_size;
    int* acnt = cnts;
    int* tcnt = cnts + N_ATOMS;

    // triplet staging aliases ei1 (consumed by k_binB2 before ei1 written)
    float4* tbuk = (float4*)ei1;

    hipMemsetAsync(cnts, 0, (size_t)2 * N_ATOMS * 4, stream);

    k_wc<<<WBLK + EBLK + TBLK, 256, 0, stream>>>(
        W_mix0, Wf0, W_mix1, Wf1, W_si1, WfS1,
        edge_src, central, acnt, tcnt);

    k_scanA<<<2, 512, 0, stream>>>(acnt, epoff, gce, tcnt, tpoff, gct);

    k_bpre<<<EBLK + TBLK + S0BLK2 + DABLK2, 512, 0, stream>>>(
        distances, sw, edge_dst, edge_src, gce, ebuk,
        angles, angle_src, angle_dst, central, gct, tbuk,
        species, table, W_si0, ei0, sd,
        dist_a, sw_a, W_da0, W_da1, dah0, dah1);

    k_binB2<<<2 * NBUK, 256, 0, stream>>>(
        epoff, acnt, gce, ebuk, erbf, edi,
        tpoff, tcnt, gct, tbuk, tpay);

    int gemm_grid = (N_ATOMS + 31) / 32;

    // ---- layer 0 ----
    k_seg<<<2 * MIBLK, 256, 0, stream>>>(epoff, erbf, edi, sd, ei0 + 80, DINP0,
                                         tpoff, tpay, dah0, ei0 + 336, DINP0);
    k_gemm<0><<<gemm_grid, 256, 0, stream>>>(ei0, Wf0, b_mix0, nullptr, nullptr, ei1);

    // ---- layer 1 ----
    k_s1<<<(N_ATOMS + 63) / 64, 256, 0, stream>>>(ei1, WfS1, ei1, sd);
    k_seg<<<2 * MIBLK, 256, 0, stream>>>(epoff, erbf, edi, sd, ei1 + 320, DINP1,
                                         tpoff, tpay, dah1, ei1 + 576, DINP1);
    k_gemm<1><<<gemm_grid, 256, 0, stream>>>(ei1, Wf1, b_mix1, ei1, out, nullptr);
}

// Round 10
// 412.965 us; speedup vs baseline: 1.3049x; 1.3049x over previous
//
#include <hip/hip_runtime.h>
#include <hip/hip_bf16.h>

typedef __hip_bfloat16 bf16;
typedef __bf16 bf8 __attribute__((ext_vector_type(8)));
typedef float  f4  __attribute__((ext_vector_type(4)));

#define N_ATOMS 25000
#define NE      800000
#define NEA     300000
#define NT      1600000
#define APB     64
#define NBUK    ((N_ATOMS + APB - 1) / APB)   // 391
#define PADB    512                            // per-bucket pad reservation (>= 64*7)

#define DIN0  376
#define DIN1  616
#define DINP0 384
#define DINP1 640

#define EBLK ((NE + 4095) / 4096)   // 196
#define TBLK ((NT + 4095) / 4096)   // 391

#define NFRAG0 ((DINP0 / 32) * 16 * 64)   // 12288
#define NFRAG1 ((DINP1 / 32) * 16 * 64)   // 20480
#define NFRAGS (8 * 6 * 64)               // 3072
#define WBLK   ((NFRAG0 + NFRAG1 + NFRAGS + 255) / 256)   // 140

#define S0BLK2 ((N_ATOMS * 120 + 511) / 512)   // 5860
#define DABLK2 ((NEA + 1 + 511) / 512)         // 587

#define MIBLK ((N_ATOMS + 1) / 2)   // 12500

__device__ __forceinline__ float tssr2f(float x) {
    float ax = fabsf(x);
    return (ax <= 1.f) ? x : copysignf(2.f * __builtin_sqrtf(ax) - 1.f, x);
}

__device__ __forceinline__ unsigned short f2bf_rn(float v) {
    unsigned int b = __float_as_uint(v);
    b += 0x7FFF + ((b >> 16) & 1);
    return (unsigned short)(b >> 16);
}
__device__ __forceinline__ float bf2f(unsigned short u) {
    return __uint_as_float(((unsigned int)u) << 16);
}

// ------------------------------------------------------------------
// k_wc (fused): blocks [0,WBLK) = W->bf16 fragment prep (3 matrices);
// rest = BUCKET-granularity counts via LDS histogram (r8-proven; r9's
// per-atom global atomics were a 112 us disaster — 2.4M RMWs on 100KB).
// ------------------------------------------------------------------
__device__ __forceinline__ void wprep_one(const float* __restrict__ W, bf8* __restrict__ Wf,
                                          int K, int N, int ntiles, int f) {
    int lane = f & 63;
    int ft = f >> 6;
    int tile = ft % ntiles;
    int chunk = ft / ntiles;
    int n = tile * 16 + (lane & 15);
    int kb = chunk * 32 + (lane >> 4) * 8;
    bf8 v;
#pragma unroll
    for (int j = 0; j < 8; j++) {
        int k = kb + j;
        v[j] = (__bf16)((k < K) ? W[k * N + n] : 0.f);
    }
    Wf[f] = v;
}

__global__ __launch_bounds__(256) void k_wc(const float* __restrict__ W0, bf8* __restrict__ Wf0,
                                            const float* __restrict__ W1, bf8* __restrict__ Wf1,
                                            const float* __restrict__ WS, bf8* __restrict__ WfS,
                                            const int* __restrict__ esrc, const int* __restrict__ cat,
                                            int* __restrict__ ebcnt, int* __restrict__ tbcnt) {
    int bid = blockIdx.x;
    int t = threadIdx.x;
    if (bid < WBLK) {
        int f = bid * 256 + t;
        if (f < NFRAG0) {
            wprep_one(W0, Wf0, DIN0, 256, 16, f);
        } else if (f < NFRAG0 + NFRAG1) {
            wprep_one(W1, Wf1, DIN1, 256, 16, f - NFRAG0);
        } else if (f < NFRAG0 + NFRAG1 + NFRAGS) {
            wprep_one(WS, WfS, 256, 96, 6, f - NFRAG0 - NFRAG1);
        }
        return;
    }
    bid -= WBLK;
    __shared__ int h[NBUK];
    for (int b = t; b < NBUK; b += 256) h[b] = 0;
    __syncthreads();
    bool isE = bid < EBLK;
    const int* key = isE ? esrc : cat;
    int n = isE ? NE : NT;
    int base = (isE ? bid : bid - EBLK) * 4096;
#pragma unroll
    for (int k = 0; k < 16; k++) {
        int idx = base + k * 256 + t;
        if (idx < n) atomicAdd(&h[key[idx] >> 6], 1);
    }
    __syncthreads();
    int* g = isE ? ebcnt : tbcnt;
    for (int b = t; b < NBUK; b += 256)
        if (h[b]) atomicAdd(&g[b], h[b]);
}

// ------------------------------------------------------------------
// k_scanB: scan 391 bucket counts -> compact staging bases (bkoff) and
// staging cursors (gcur). Final (padded) base of bucket b is derived
// in-kernel later as bkoff[b] + b*PADB.
// ------------------------------------------------------------------
__global__ __launch_bounds__(512) void k_scanB(const int* cnt0, int* off0, int* cur0,
                                               const int* cnt1, int* off1, int* cur1) {
    const int* cnt = blockIdx.x ? cnt1 : cnt0;
    int* off = blockIdx.x ? off1 : off0;
    int* cur = blockIdx.x ? cur1 : cur0;
    __shared__ int sh[512];
    int t = threadIdx.x;
    int v = (t < NBUK) ? cnt[t] : 0;
    sh[t] = v;
    __syncthreads();
    for (int d = 1; d < 512; d <<= 1) {
        int a = (t >= d) ? sh[t - d] : 0;
        __syncthreads();
        sh[t] += a;
        __syncthreads();
    }
    int excl = sh[t] - v;
    if (t <= NBUK) { off[t] = excl; if (t < NBUK) cur[t] = excl; }
}

// ------------------------------------------------------------------
// k_bpre (fused): blocks [0, EBLK+TBLK) = phase-A binning (staging
// into coarse compact buckets); then layer-0 species/si fill (ei0
// bf16); then da for BOTH layers (+ zero sentinel row at NEA so
// triplet pads contribute exactly 0).
// ------------------------------------------------------------------
__global__ __launch_bounds__(512) void k_bpre(const float* __restrict__ eA,
                                              const float* __restrict__ eB,
                                              const int* __restrict__ eC,
                                              const int* __restrict__ ekey,
                                              int* __restrict__ egcur,
                                              float4* __restrict__ ebuk,
                                              const float* __restrict__ tA,
                                              const int* __restrict__ tB,
                                              const int* __restrict__ tC,
                                              const int* __restrict__ tkey,
                                              int* __restrict__ tgcur,
                                              float4* __restrict__ tbuk,
                                              const int* __restrict__ sp,
                                              const float* __restrict__ table,
                                              const float* __restrict__ Wsi,
                                              unsigned short* __restrict__ ei0,
                                              float* __restrict__ sd,
                                              const float* __restrict__ dist,
                                              const float* __restrict__ sw2,
                                              const float* __restrict__ Wda0,
                                              const float* __restrict__ Wda1,
                                              unsigned short* __restrict__ dah0,
                                              unsigned short* __restrict__ dah1) {
    int bid = blockIdx.x;
    int t = threadIdx.x;
    if (bid < EBLK + TBLK) {
        __shared__ int cnt[NBUK];
        __shared__ int rbase[NBUK];
        for (int b = t; b < NBUK; b += 512) cnt[b] = 0;
        __syncthreads();
        bool isE = bid < EBLK;
        const int* key = isE ? ekey : tkey;
        int n = isE ? NE : NT;
        int* gcur = isE ? egcur : tgcur;
        float4* buk = isE ? ebuk : tbuk;
        int base = (isE ? bid : (bid - EBLK)) * 4096;
        float4 pay[8];
        int bk[8], off[8];
#pragma unroll
        for (int k = 0; k < 8; k++) {
            int idx = base + k * 512 + t;
            bk[k] = -1;
            if (idx < n) {
                float4 p;
                if (isE) {
                    p.x = eA[idx];
                    p.y = eB[idx];
                    p.z = __int_as_float(eC[idx]);
                } else {
                    p.x = __cosf(tA[idx]);
                    p.y = __int_as_float(tB[idx]);
                    p.z = __int_as_float(tC[idx]);
                }
                int ky = key[idx];
                p.w = __int_as_float(ky);
                pay[k] = p;
                bk[k] = ky >> 6;
                off[k] = atomicAdd(&cnt[bk[k]], 1);
            }
        }
        __syncthreads();
        for (int b = t; b < NBUK; b += 512)
            if (cnt[b]) rbase[b] = atomicAdd(&gcur[b], cnt[b]);
        __syncthreads();
#pragma unroll
        for (int k = 0; k < 8; k++)
            if (bk[k] >= 0) buk[rbase[bk[k]] + off[k]] = pay[k];
    } else if (bid < EBLK + TBLK + S0BLK2) {
        int idx = (bid - EBLK - TBLK) * 512 + t;
        if (idx >= N_ATOMS * 120) return;
        int i = idx / 120;
        int c = idx - i * 120;
        if (c >= 112) {
            ei0[(size_t)i * DINP0 + 376 + (c - 112)] = 0;
            return;
        }
        int s = sp[i];
        if (c < 16) {
            ei0[(size_t)i * DINP0 + c] = f2bf_rn(table[s * 16 + c]);
        } else {
            int cc = c - 16;
            float acc = 0.f;
#pragma unroll
            for (int k = 0; k < 16; k++)
                acc += table[s * 16 + k] * Wsi[k * 96 + cc];
            if (cc < 64) ei0[(size_t)i * DINP0 + 16 + cc] = f2bf_rn(acc);
            else         sd[i * 32 + cc - 64]             = acc;
        }
    } else {
        int e = (bid - EBLK - TBLK - S0BLK2) * 512 + t;
        if (e > NEA) return;
        if (e == NEA) {   // sentinel row: triplet pads index here -> dij = 0
            uint4 z = make_uint4(0, 0, 0, 0);
            *(uint4*)&dah0[(size_t)e * 8] = z;
            *(uint4*)&dah1[(size_t)e * 8] = z;
            return;
        }
        float d = dist[e];
        float s = sw2[e];
        float rb[8];
#pragma unroll
        for (int n = 0; n < 8; n++)
            rb[n] = 0.7559289460f * __sinf((n + 1) * 0.8975979010f * d) / d * s;
        unsigned short h0[8], h1[8];
#pragma unroll
        for (int c = 0; c < 8; c++) {
            float a0 = 0.f, a1 = 0.f;
#pragma unroll
            for (int n = 0; n < 8; n++) {
                a0 += rb[n] * Wda0[n * 8 + c];
                a1 += rb[n] * Wda1[n * 8 + c];
            }
            h0[c] = f2bf_rn(a0);
            h1[c] = f2bf_rn(a1);
        }
        *(uint4*)&dah0[e * 8] = *(uint4*)h0;
        *(uint4*)&dah1[e * 8] = *(uint4*)h1;
    }
}

// ------------------------------------------------------------------
// k_binB2: one workgroup per bucket; blocks [0,NBUK) edges, rest
// triplets. Counts per-atom from staged payloads (LDS), computes
// per-atom PADDED bases within the bucket's padded region
// (fbase = bkoff[b] + b*PADB), writes ebase/epcnt (tbase/tpcnt),
// zero-fills pad slots, then scatters. EDGES: rb[8] written
// GROUP-TRANSPOSED ([n][j] per 8-edge group) so k_seg reads rb with
// two broadcast float4 loads (no shfl, no masks).
// ------------------------------------------------------------------
__global__ __launch_bounds__(256) void k_binB2(const int* __restrict__ ebkoff,
                                               const int* __restrict__ ebcnt,
                                               const float4* __restrict__ ebuk,
                                               float* __restrict__ erb,
                                               int* __restrict__ edi,
                                               int* __restrict__ ebase_g,
                                               int* __restrict__ epcnt_g,
                                               const int* __restrict__ tbkoff,
                                               const int* __restrict__ tbcnt,
                                               const float4* __restrict__ tbuk,
                                               float4* __restrict__ tpay,
                                               int* __restrict__ tbase_g,
                                               int* __restrict__ tpcnt_g) {
    bool isE = blockIdx.x < NBUK;
    int b = isE ? blockIdx.x : (blockIdx.x - NBUK);
    const int* bkoff = isE ? ebkoff : tbkoff;
    const int* bkcnt = isE ? ebcnt : tbcnt;
    const float4* buk = isE ? ebuk : tbuk;
    int* baseg = isE ? ebase_g : tbase_g;
    int* pcntg = isE ? epcnt_g : tpcnt_g;
    int lo = b * APB;
    int hi = min(lo + APB, N_ATOMS);
    int sbase = bkoff[b];
    int bc = bkcnt[b];
    int fb = sbase + b * PADB;   // padded final base of this bucket
    __shared__ int cntA[APB];
    __shared__ int abase[APB];
    __shared__ int cur[APB];
    int t = threadIdx.x;
    if (t < APB) cntA[t] = 0;
    __syncthreads();
    for (int p = sbase + t; p < sbase + bc; p += 256) {
        int a = __float_as_int(((const float*)(buk + p))[3]);
        atomicAdd(&cntA[a - lo], 1);
    }
    __syncthreads();
    if (t == 0) {
        int run = fb;
        for (int k = 0; k < hi - lo; k++) {
            int pc = (cntA[k] + 7) & ~7;
            abase[k] = run;
            cur[k] = run;
            baseg[lo + k] = run;
            pcntg[lo + k] = pc;
            run += pc;
        }
    }
    __syncthreads();
    // zero-fill pad slots
    if (t < hi - lo) {
        int c = cntA[t];
        int pc = (c + 7) & ~7;
        int base = abase[t];
        if (isE) {
            for (int s = base + c; s < base + pc; s++) {
                edi[s] = 0;
                int pos = s - base;
                float* dz = erb + ((size_t)base + (pos & ~7)) * 8 + (pos & 7);
#pragma unroll
                for (int nn = 0; nn < 8; nn++) dz[nn * 8] = 0.f;
            }
        } else {
            float4 pz = make_float4(0.f, __int_as_float(NEA), __int_as_float(NEA), 0.f);
            for (int s = base + c; s < base + pc; s++) tpay[s] = pz;
        }
    }
    __syncthreads();
    for (int p = sbase + t; p < sbase + bc; p += 256) {
        float4 pay = buk[p];
        int a = __float_as_int(pay.w);
        int k = a - lo;
        int slot = atomicAdd(&cur[k], 1);
        if (isE) {
            float d = pay.x, s2 = pay.y;
            float q = 0.6324555320f * s2 / d;
            int pos = slot - abase[k];
            float* dst = erb + ((size_t)abase[k] + (pos & ~7)) * 8 + (pos & 7);
#pragma unroll
            for (int nn = 0; nn < 8; nn++)
                dst[nn * 8] = q * __sinf((nn + 1) * 0.6283185307f * d);
            edi[slot] = __float_as_int(pay.z);
        } else {
            tpay[slot] = pay;
        }
    }
}

// ------------------------------------------------------------------
// layer 1 s: MFMA GEMM 25000x96 (ei1 bf16: A-staging is raw 16B copy)
// ------------------------------------------------------------------
__global__ __launch_bounds__(256) void k_s1(const unsigned short* __restrict__ ei1,
                                            const bf8* __restrict__ Wf,
                                            unsigned short* __restrict__ ei1o,
                                            float* __restrict__ sd) {
    __shared__ __align__(16) __bf16 Asg[4][64][8];
    int t = threadIdx.x;
    int w = t >> 6, lane = t & 63;
    int a0 = blockIdx.x * 64;

    int satom = a0 + (t >> 2);
    int k8 = (t & 3) * 8;
    const unsigned short* arow = &ei1[(size_t)satom * DINP1 + k8];
    bool aok = satom < N_ATOMS;
    int dw = (t >> 2) >> 4;
    int dl = ((t >> 2) & 15) | ((t & 3) << 4);
    __bf16* adst = &Asg[dw][dl][0];

    f4 acc[6];
#pragma unroll
    for (int j = 0; j < 6; j++) {
        f4 z = {0.f, 0.f, 0.f, 0.f};
        acc[j] = z;
    }

    for (int ch = 0; ch < 8; ch++) {
        uint4 v = make_uint4(0, 0, 0, 0);
        if (aok) v = *(const uint4*)(arow + ch * 32);
        __syncthreads();
        *(uint4*)adst = v;
        __syncthreads();
        bf8 afr = *(const bf8*)&Asg[w][lane][0];
        const bf8* wp = &Wf[(ch * 6) * 64 + lane];
#pragma unroll
        for (int tn = 0; tn < 6; tn++) {
            bf8 b = wp[tn * 64];
            acc[tn] = __builtin_amdgcn_mfma_f32_16x16x32_bf16(afr, b, acc[tn], 0, 0, 0);
        }
    }

    int nlo = lane & 15, q = lane >> 4;
#pragma unroll
    for (int r = 0; r < 4; r++) {
        int atom = a0 + w * 16 + q * 4 + r;
        if (atom < N_ATOMS) {
#pragma unroll
            for (int tn = 0; tn < 6; tn++) {
                int col = tn * 16 + nlo;
                float v = acc[tn][r];
                if (col < 64) ei1o[(size_t)atom * DINP1 + 256 + col] = f2bf_rn(v);
                else          sd[atom * 32 + col - 64] = v;
            }
        }
    }
    for (int z = t; z < 64 * 24; z += 256) {
        int za = a0 + z / 24;
        if (za < N_ATOMS) ei1o[(size_t)za * DINP1 + 616 + z % 24] = 0;
    }
}

// ------------------------------------------------------------------
// ami window helper (MASKLESS: pads are sentinel triplets with cos=0
// and dah-row 0 -> contribute exactly 0). 1-deep dah prefetch.
// ------------------------------------------------------------------
__device__ __forceinline__ void ami_win(const float4 twA, const unsigned short* __restrict__ dah,
                                        int gmax, int jj, int c,
                                        float& a0, float& a1, float& a2, float& a3, float& a4) {
    float sc = 0.f; unsigned short dA = 0, dB = 0;
    {
        sc = __shfl(twA.x, jj, 64);
        int ea = __float_as_int(__shfl(twA.y, jj, 64));
        int eb = __float_as_int(__shfl(twA.z, jj, 64));
        dA = dah[ea * 8 + c];
        dB = dah[eb * 8 + c];
    }
    for (int g = 0; g < gmax; g++) {
        float scN = 0.f; unsigned short dAN = 0, dBN = 0;
        if (g + 1 < gmax) {
            int sl = (g + 1) * 8 + jj;
            scN = __shfl(twA.x, sl, 64);
            int ea = __float_as_int(__shfl(twA.y, sl, 64));
            int eb = __float_as_int(__shfl(twA.z, sl, 64));
            dAN = dah[ea * 8 + c];
            dBN = dah[eb * 8 + c];
        }
        float dij = bf2f(dA) * bf2f(dB);
        float c1 = sc;
        float c2 = __builtin_fmaf(2.f * c1, c1, -1.f);
        float c3 = __builtin_fmaf(2.f * c1, c2, -c1);
        float c4 = __builtin_fmaf(2.f * c1, c3, -c2);
        a0 += dij;
        a1 = __builtin_fmaf(c1, dij, a1);
        a2 = __builtin_fmaf(c2, dij, a2);
        a3 = __builtin_fmaf(c3, dij, a3);
        a4 = __builtin_fmaf(c4, dij, a4);
        if (g + 1 < gmax) { sc = scN; dA = dAN; dB = dBN; }
    }
}

// ------------------------------------------------------------------
// k_seg: 2 atoms/block, 2 waves/atom (r6-proven). ami blocks first
// (LPT). PADDED per-atom regions + group-transposed erb: the mi inner
// loop has NO shfl for rb (two broadcast float4 loads) and NO masks
// anywhere (pads = exact zeros).
// ------------------------------------------------------------------
__global__ __launch_bounds__(256) void k_seg(const int* __restrict__ ebase,
                                             const int* __restrict__ epcnt,
                                             const float* __restrict__ erb,
                                             const int* __restrict__ edi,
                                             const float* __restrict__ sd,
                                             unsigned short* __restrict__ mo, int mstride,
                                             const int* __restrict__ tbase,
                                             const int* __restrict__ tpcnt,
                                             const float4* __restrict__ tpay,
                                             const unsigned short* __restrict__ dah,
                                             unsigned short* __restrict__ ao, int astride) {
    __shared__ float4 smi[2][64];
    __shared__ float  sam[2][5][8];
    int t = threadIdx.x;
    int wv = t >> 6, l = t & 63;
    int slot = wv >> 1;
    int p    = wv & 1;

    if ((int)blockIdx.x < MIBLK) {
        // ---------------- ami ----------------
        int i = blockIdx.x * 2 + slot;
        bool valid = (i < N_ATOMS);
        int pbeg = 0, pcnt = 0;
        if (valid) { pbeg = tbase[i]; pcnt = tpcnt[i]; }
        int jj = l >> 3, c = l & 7;
        float a0 = 0.f, a1 = 0.f, a2 = 0.f, a3 = 0.f, a4 = 0.f;

        if (pcnt > 0) {
            int nG = pcnt >> 3;
            if (pcnt <= 128) {
                int h0 = (nG + 1) >> 1;
                int gb = p ? h0 : 0;
                int myg = p ? (nG - h0) : h0;
                if (myg > 0) {
                    int tb = gb * 8;
                    float4 twA = tpay[pbeg + tb + min(l, myg * 8 - 1)];
                    ami_win(twA, dah, myg, jj, c, a0, a1, a2, a3, a4);
                }
            } else {
                int nW = (pcnt + 63) >> 6;
                for (int W = p; W < nW; W += 2) {
                    int wbase = W * 64;
                    int rem = pcnt - wbase;
                    int lim = min(rem, 64);
                    float4 twA = tpay[pbeg + wbase + min(l, rem - 1)];
                    ami_win(twA, dah, lim >> 3, jj, c, a0, a1, a2, a3, a4);
                }
            }
        }

        // reduce over jj within wave (lanes l, l^8, l^16, l^32)
#pragma unroll
        for (int msk = 8; msk <= 32; msk <<= 1) {
            a0 += __shfl_xor(a0, msk, 64);
            a1 += __shfl_xor(a1, msk, 64);
            a2 += __shfl_xor(a2, msk, 64);
            a3 += __shfl_xor(a3, msk, 64);
            a4 += __shfl_xor(a4, msk, 64);
        }
        if (p == 1 && l < 8) {
            sam[slot][0][l] = a0; sam[slot][1][l] = a1; sam[slot][2][l] = a2;
            sam[slot][3][l] = a3; sam[slot][4][l] = a4;
        }
        __syncthreads();
        if (valid && p == 0 && l < 8) {
            a0 += sam[slot][0][l]; a1 += sam[slot][1][l]; a2 += sam[slot][2][l];
            a3 += sam[slot][3][l]; a4 += sam[slot][4][l];
            unsigned short* o = &ao[(size_t)i * astride + c];
            o[0]  = f2bf_rn(a0);
            o[8]  = f2bf_rn(a1);
            o[16] = f2bf_rn(a2);
            o[24] = f2bf_rn(a3);
            o[32] = f2bf_rn(a4);
        }
    } else {
        // ---------------- mi ----------------
        int i = ((int)blockIdx.x - MIBLK) * 2 + slot;
        bool valid = (i < N_ATOMS);
        int pbeg = 0, pcnt = 0;
        if (valid) { pbeg = ebase[i]; pcnt = epcnt[i]; }
        int n = l >> 3, cb = (l & 7) * 4;
        float4 acc = make_float4(0.f, 0.f, 0.f, 0.f);

        if (pcnt > 0) {
            int nG = pcnt >> 3;
            int h0 = (nG + 1) >> 1;
            int gbeg = p ? h0 : 0;
            int gend = p ? nG : h0;
            if (pcnt <= 64) {
                int eWin = edi[pbeg + min(l, pcnt - 1)];
                for (int g = gbeg; g < gend; g++) {
                    const float* rp = erb + ((size_t)pbeg + g * 8) * 8 + n * 8;
                    f4 rA = *(const f4*)rp;
                    f4 rB = *(const f4*)(rp + 4);
                    float4 v[8];
#pragma unroll
                    for (int j = 0; j < 8; j++) {
                        int eid = __shfl(eWin, g * 8 + j, 64);
                        v[j] = *(const float4*)&sd[eid * 32 + cb];
                    }
#pragma unroll
                    for (int j = 0; j < 8; j++) {
                        float rbj = (j < 4) ? rA[j] : rB[j - 4];
                        acc.x += rbj * v[j].x; acc.y += rbj * v[j].y;
                        acc.z += rbj * v[j].z; acc.w += rbj * v[j].w;
                    }
                }
            } else {
                const int* dp = edi + pbeg;
                for (int g = gbeg; g < gend; g++) {
                    const float* rp = erb + ((size_t)pbeg + g * 8) * 8 + n * 8;
                    f4 rA = *(const f4*)rp;
                    f4 rB = *(const f4*)(rp + 4);
                    float4 v[8];
#pragma unroll
                    for (int j = 0; j < 8; j++) {
                        int eid = dp[g * 8 + j];
                        v[j] = *(const float4*)&sd[eid * 32 + cb];
                    }
#pragma unroll
                    for (int j = 0; j < 8; j++) {
                        float rbj = (j < 4) ? rA[j] : rB[j - 4];
                        acc.x += rbj * v[j].x; acc.y += rbj * v[j].y;
                        acc.z += rbj * v[j].z; acc.w += rbj * v[j].w;
                    }
                }
            }
        }

        if (p == 1) smi[slot][l] = acc;
        __syncthreads();
        if (valid && p == 0) {
            float4 o = smi[slot][l];
            acc.x += o.x; acc.y += o.y; acc.z += o.z; acc.w += o.w;
            ushort4 pk = make_ushort4(f2bf_rn(acc.x), f2bf_rn(acc.y),
                                      f2bf_rn(acc.z), f2bf_rn(acc.w));
            *(ushort4*)&mo[(size_t)i * mstride + l * 4] = pk;   // n*32+cb == l*4
        }
    }
}

// ------------------------------------------------------------------
// MFMA GEMM: dxi = tssr2(ei @ W + b). ei bf16 (raw 8B A-staging).
// LAYER 0 writes bf16 ei1; LAYER 1 writes fp32 out with bf16 skip.
// ------------------------------------------------------------------
template <int LAYER>
__global__ __launch_bounds__(256) void k_gemm(const unsigned short* __restrict__ ei,
                                              const bf8* __restrict__ Wf,
                                              const float* __restrict__ bias,
                                              const unsigned short* __restrict__ skip,
                                              float* __restrict__ outf,
                                              unsigned short* __restrict__ outb) {
    constexpr int DINP = (LAYER == 0) ? DINP0 : DINP1;
    constexpr int NCH = DINP / 32;
    __shared__ __align__(16) __bf16 Asg[2][64][8];
    int t = threadIdx.x;
    int w = t >> 6, lane = t & 63;
    int a0 = blockIdx.x * 32;

    int f  = t * 4;
    int tA = f >> 9;
    int al = (f >> 3) & 63;
    int j0 = f & 7;
    int sm = al & 15, sq = al >> 4;
    int ga = a0 + tA * 16 + sm;
    const unsigned short* arow = &ei[(size_t)ga * DINP + sq * 8 + j0];
    __bf16* adst = &Asg[0][0][0] + f;
    bool aok = (ga < N_ATOMS);

    f4 acc[2][4];
#pragma unroll
    for (int i = 0; i < 2; i++)
#pragma unroll
        for (int j = 0; j < 4; j++) {
            f4 z = {0.f, 0.f, 0.f, 0.f};
            acc[i][j] = z;
        }

    for (int ch = 0; ch < NCH; ch++) {
        uint2 v = make_uint2(0, 0);
        if (aok) v = *(const uint2*)(arow + ch * 32);
        __syncthreads();
        *(uint2*)adst = v;
        __syncthreads();
        bf8 afr0 = *(const bf8*)&Asg[0][lane][0];
        bf8 afr1 = *(const bf8*)&Asg[1][lane][0];
        const bf8* wp = &Wf[(ch * 16 + w * 4) * 64 + lane];
#pragma unroll
        for (int tn = 0; tn < 4; tn++) {
            bf8 b = wp[tn * 64];
            acc[0][tn] = __builtin_amdgcn_mfma_f32_16x16x32_bf16(afr0, b, acc[0][tn], 0, 0, 0);
            acc[1][tn] = __builtin_amdgcn_mfma_f32_16x16x32_bf16(afr1, b, acc[1][tn], 0, 0, 0);
        }
    }

    int nlo = lane & 15, q = lane >> 4;
#pragma unroll
    for (int tA2 = 0; tA2 < 2; tA2++) {
#pragma unroll
        for (int r = 0; r < 4; r++) {
            int atom = a0 + tA2 * 16 + q * 4 + r;
            if (atom < N_ATOMS) {
#pragma unroll
                for (int tn = 0; tn < 4; tn++) {
                    int col = w * 64 + tn * 16 + nlo;
                    float vv = tssr2f(acc[tA2][tn][r] + bias[col]);
                    if (LAYER == 0) {
                        outb[(size_t)atom * DINP1 + col] = f2bf_rn(vv);
                    } else {
                        outf[(size_t)atom * 256 + col] =
                            vv + bf2f(skip[(size_t)atom * DINP1 + col]);
                    }
                }
            }
        }
    }
}

// ------------------------------------------------------------------
extern "C" void kernel_launch(void* const* d_in, const int* in_sizes, int n_in,
                              void* d_out, int out_size, void* d_ws, size_t ws_size,
                              hipStream_t stream) {
    const int*   species     = (const int*)d_in[0];
    const int*   edge_src    = (const int*)d_in[1];
    const int*   edge_dst    = (const int*)d_in[2];
    const float* distances   = (const float*)d_in[3];
    const float* sw          = (const float*)d_in[4];
    const float* angles      = (const float*)d_in[5];
    const int*   angle_src   = (const int*)d_in[6];
    const int*   angle_dst   = (const int*)d_in[7];
    const int*   central     = (const int*)d_in[8];
    const float* dist_a      = (const float*)d_in[9];
    const float* sw_a        = (const float*)d_in[10];
    const float* table       = (const float*)d_in[11];
    const float* W_si0       = (const float*)d_in[12];
    const float* W_si1       = (const float*)d_in[13];
    const float* W_da0       = (const float*)d_in[14];
    const float* W_da1       = (const float*)d_in[15];
    const float* W_mix0      = (const float*)d_in[16];
    const float* b_mix0      = (const float*)d_in[17];
    const float* W_mix1      = (const float*)d_in[18];
    const float* b_mix1      = (const float*)d_in[19];
    float* out = (float*)d_out;

    char* p = (char*)d_ws;
    auto alloc = [&](size_t bytes) {
        char* r = p;
        p += (bytes + 255) & ~(size_t)255;
        return (void*)r;
    };
    unsigned short* ei0 = (unsigned short*)alloc((size_t)N_ATOMS * DINP0 * 2);
    unsigned short* ei1 = (unsigned short*)alloc((size_t)N_ATOMS * DINP1 * 2);
    float*  sd   = (float*)alloc((size_t)N_ATOMS * 32 * 4);
    unsigned short* dah0 = (unsigned short*)alloc((size_t)(NEA + 1) * 8 * 2);
    unsigned short* dah1 = (unsigned short*)alloc((size_t)(NEA + 1) * 8 * 2);
    float*  erbf = (float*)alloc((size_t)(NE + NBUK * PADB) * 8 * 4);
    int*    edi  = (int*)alloc((size_t)(NE + NBUK * PADB) * 4);
    float4* tpay = (float4*)alloc((size_t)(NT + NBUK * PADB) * 16);
    float4* ebuk = (float4*)alloc((size_t)NE * 16);
    bf8*    Wf0  = (bf8*)alloc((size_t)NFRAG0 * 16);
    bf8*    Wf1  = (bf8*)alloc((size_t)NFRAG1 * 16);
    bf8*    WfS1 = (bf8*)alloc((size_t)NFRAGS * 16);
    int* ebase  = (int*)alloc((size_t)N_ATOMS * 4);
    int* epcnt  = (int*)alloc((size_t)N_ATOMS * 4);
    int* tbase  = (int*)alloc((size_t)N_ATOMS * 4);
    int* tpcnt  = (int*)alloc((size_t)N_ATOMS * 4);
    int* bcnt   = (int*)alloc((size_t)2 * NBUK * 4);   // ebcnt | tbcnt (one memset)
    int* ebkoff = (int*)alloc((size_t)(NBUK + 1) * 4);
    int* tbkoff = (int*)alloc((size_t)(NBUK + 1) * 4);
    int* gce    = (int*)alloc((size_t)NBUK * 4);
    int* gct    = (int*)alloc((size_t)NBUK * 4);
    (void)ws_size;
    int* ebcnt = bcnt;
    int* tbcnt = bcnt + NBUK;

    // triplet staging aliases ei1 (consumed by k_binB2 before ei1 written)
    float4* tbuk = (float4*)ei1;

    hipMemsetAsync(bcnt, 0, (size_t)2 * NBUK * 4, stream);

    k_wc<<<WBLK + EBLK + TBLK, 256, 0, stream>>>(
        W_mix0, Wf0, W_mix1, Wf1, W_si1, WfS1,
        edge_src, central, ebcnt, tbcnt);

    k_scanB<<<2, 512, 0, stream>>>(ebcnt, ebkoff, gce, tbcnt, tbkoff, gct);

    k_bpre<<<EBLK + TBLK + S0BLK2 + DABLK2, 512, 0, stream>>>(
        distances, sw, edge_dst, edge_src, gce, ebuk,
        angles, angle_src, angle_dst, central, gct, tbuk,
        species, table, W_si0, ei0, sd,
        dist_a, sw_a, W_da0, W_da1, dah0, dah1);

    k_binB2<<<2 * NBUK, 256, 0, stream>>>(
        ebkoff, ebcnt, ebuk, erbf, edi, ebase, epcnt,
        tbkoff, tbcnt, tbuk, tpay, tbase, tpcnt);

    int gemm_grid = (N_ATOMS + 31) / 32;

    // ---- layer 0 ----
    k_seg<<<2 * MIBLK, 256, 0, stream>>>(ebase, epcnt, erbf, edi, sd, ei0 + 80, DINP0,
                                         tbase, tpcnt, tpay, dah0, ei0 + 336, DINP0);
    k_gemm<0><<<gemm_grid, 256, 0, stream>>>(ei0, Wf0, b_mix0, nullptr, nullptr, ei1);

    // ---- layer 1 ----
    k_s1<<<(N_ATOMS + 63) / 64, 256, 0, stream>>>(ei1, WfS1, ei1, sd);
    k_seg<<<2 * MIBLK, 256, 0, stream>>>(ebase, epcnt, erbf, edi, sd, ei1 + 320, DINP1,
                                         tbase, tpcnt, tpay, dah1, ei1 + 576, DINP1);
    k_gemm<1><<<gemm_grid, 256, 0, stream>>>(ei1, Wf1, b_mix1, ei1, out, nullptr);
}

// Round 11
// 400.983 us; speedup vs baseline: 1.3439x; 1.0299x over previous
//
#include <hip/hip_runtime.h>
#include <hip/hip_bf16.h>

typedef __hip_bfloat16 bf16;
typedef __bf16 bf8 __attribute__((ext_vector_type(8)));
typedef float  f4  __attribute__((ext_vector_type(4)));

#define N_ATOMS 25000
#define NE      800000
#define NEA     300000
#define NT      1600000
#define APB     64
#define NBUK    ((N_ATOMS + APB - 1) / APB)   // 391
#define PADB    512                            // per-bucket pad reservation (>= 64*7)

#define DIN0  376
#define DIN1  616
#define DINP0 384
#define DINP1 640

#define EBLK ((NE + 4095) / 4096)   // 196
#define TBLK ((NT + 4095) / 4096)   // 391

#define NFRAG0 ((DINP0 / 32) * 16 * 64)   // 12288
#define NFRAG1 ((DINP1 / 32) * 16 * 64)   // 20480
#define NFRAGS (8 * 6 * 64)               // 3072
#define WBLK   ((NFRAG0 + NFRAG1 + NFRAGS + 255) / 256)   // 140

#define S0BLK2 ((N_ATOMS * 120 + 511) / 512)   // 5860
#define DABLK2 ((NEA + 1 + 511) / 512)         // 587

#define MIBLK ((N_ATOMS + 1) / 2)   // 12500

__device__ __forceinline__ float tssr2f(float x) {
    float ax = fabsf(x);
    return (ax <= 1.f) ? x : copysignf(2.f * __builtin_sqrtf(ax) - 1.f, x);
}

__device__ __forceinline__ unsigned short f2bf_rn(float v) {
    unsigned int b = __float_as_uint(v);
    b += 0x7FFF + ((b >> 16) & 1);
    return (unsigned short)(b >> 16);
}
__device__ __forceinline__ float bf2f(unsigned short u) {
    return __uint_as_float(((unsigned int)u) << 16);
}

// ------------------------------------------------------------------
// k_wc (fused): blocks [0,WBLK) = W->bf16 fragment prep (3 matrices);
// rest = BUCKET-granularity counts via LDS histogram (r8-proven).
// ------------------------------------------------------------------
__device__ __forceinline__ void wprep_one(const float* __restrict__ W, bf8* __restrict__ Wf,
                                          int K, int N, int ntiles, int f) {
    int lane = f & 63;
    int ft = f >> 6;
    int tile = ft % ntiles;
    int chunk = ft / ntiles;
    int n = tile * 16 + (lane & 15);
    int kb = chunk * 32 + (lane >> 4) * 8;
    bf8 v;
#pragma unroll
    for (int j = 0; j < 8; j++) {
        int k = kb + j;
        v[j] = (__bf16)((k < K) ? W[k * N + n] : 0.f);
    }
    Wf[f] = v;
}

__global__ __launch_bounds__(256) void k_wc(const float* __restrict__ W0, bf8* __restrict__ Wf0,
                                            const float* __restrict__ W1, bf8* __restrict__ Wf1,
                                            const float* __restrict__ WS, bf8* __restrict__ WfS,
                                            const int* __restrict__ esrc, const int* __restrict__ cat,
                                            int* __restrict__ ebcnt, int* __restrict__ tbcnt) {
    int bid = blockIdx.x;
    int t = threadIdx.x;
    if (bid < WBLK) {
        int f = bid * 256 + t;
        if (f < NFRAG0) {
            wprep_one(W0, Wf0, DIN0, 256, 16, f);
        } else if (f < NFRAG0 + NFRAG1) {
            wprep_one(W1, Wf1, DIN1, 256, 16, f - NFRAG0);
        } else if (f < NFRAG0 + NFRAG1 + NFRAGS) {
            wprep_one(WS, WfS, 256, 96, 6, f - NFRAG0 - NFRAG1);
        }
        return;
    }
    bid -= WBLK;
    __shared__ int h[NBUK];
    for (int b = t; b < NBUK; b += 256) h[b] = 0;
    __syncthreads();
    bool isE = bid < EBLK;
    const int* key = isE ? esrc : cat;
    int n = isE ? NE : NT;
    int base = (isE ? bid : bid - EBLK) * 4096;
#pragma unroll
    for (int k = 0; k < 16; k++) {
        int idx = base + k * 256 + t;
        if (idx < n) atomicAdd(&h[key[idx] >> 6], 1);
    }
    __syncthreads();
    int* g = isE ? ebcnt : tbcnt;
    for (int b = t; b < NBUK; b += 256)
        if (h[b]) atomicAdd(&g[b], h[b]);
}

// ------------------------------------------------------------------
// k_scanB: scan 391 bucket counts -> compact staging bases (bkoff) and
// staging cursors (gcur). Padded base of bucket b = bkoff[b] + b*PADB.
// ------------------------------------------------------------------
__global__ __launch_bounds__(512) void k_scanB(const int* cnt0, int* off0, int* cur0,
                                               const int* cnt1, int* off1, int* cur1) {
    const int* cnt = blockIdx.x ? cnt1 : cnt0;
    int* off = blockIdx.x ? off1 : off0;
    int* cur = blockIdx.x ? cur1 : cur0;
    __shared__ int sh[512];
    int t = threadIdx.x;
    int v = (t < NBUK) ? cnt[t] : 0;
    sh[t] = v;
    __syncthreads();
    for (int d = 1; d < 512; d <<= 1) {
        int a = (t >= d) ? sh[t - d] : 0;
        __syncthreads();
        sh[t] += a;
        __syncthreads();
    }
    int excl = sh[t] - v;
    if (t <= NBUK) { off[t] = excl; if (t < NBUK) cur[t] = excl; }
}

// ------------------------------------------------------------------
// k_bpre (fused): phase-A binning; layer-0 species/si fill (bf16);
// da for BOTH layers (+ zero sentinel row at NEA).
// ------------------------------------------------------------------
__global__ __launch_bounds__(512) void k_bpre(const float* __restrict__ eA,
                                              const float* __restrict__ eB,
                                              const int* __restrict__ eC,
                                              const int* __restrict__ ekey,
                                              int* __restrict__ egcur,
                                              float4* __restrict__ ebuk,
                                              const float* __restrict__ tA,
                                              const int* __restrict__ tB,
                                              const int* __restrict__ tC,
                                              const int* __restrict__ tkey,
                                              int* __restrict__ tgcur,
                                              float4* __restrict__ tbuk,
                                              const int* __restrict__ sp,
                                              const float* __restrict__ table,
                                              const float* __restrict__ Wsi,
                                              unsigned short* __restrict__ ei0,
                                              float* __restrict__ sd,
                                              const float* __restrict__ dist,
                                              const float* __restrict__ sw2,
                                              const float* __restrict__ Wda0,
                                              const float* __restrict__ Wda1,
                                              unsigned short* __restrict__ dah0,
                                              unsigned short* __restrict__ dah1) {
    int bid = blockIdx.x;
    int t = threadIdx.x;
    if (bid < EBLK + TBLK) {
        __shared__ int cnt[NBUK];
        __shared__ int rbase[NBUK];
        for (int b = t; b < NBUK; b += 512) cnt[b] = 0;
        __syncthreads();
        bool isE = bid < EBLK;
        const int* key = isE ? ekey : tkey;
        int n = isE ? NE : NT;
        int* gcur = isE ? egcur : tgcur;
        float4* buk = isE ? ebuk : tbuk;
        int base = (isE ? bid : (bid - EBLK)) * 4096;
        float4 pay[8];
        int bk[8], off[8];
#pragma unroll
        for (int k = 0; k < 8; k++) {
            int idx = base + k * 512 + t;
            bk[k] = -1;
            if (idx < n) {
                float4 p;
                if (isE) {
                    p.x = eA[idx];
                    p.y = eB[idx];
                    p.z = __int_as_float(eC[idx]);
                } else {
                    p.x = __cosf(tA[idx]);
                    p.y = __int_as_float(tB[idx]);
                    p.z = __int_as_float(tC[idx]);
                }
                int ky = key[idx];
                p.w = __int_as_float(ky);
                pay[k] = p;
                bk[k] = ky >> 6;
                off[k] = atomicAdd(&cnt[bk[k]], 1);
            }
        }
        __syncthreads();
        for (int b = t; b < NBUK; b += 512)
            if (cnt[b]) rbase[b] = atomicAdd(&gcur[b], cnt[b]);
        __syncthreads();
#pragma unroll
        for (int k = 0; k < 8; k++)
            if (bk[k] >= 0) buk[rbase[bk[k]] + off[k]] = pay[k];
    } else if (bid < EBLK + TBLK + S0BLK2) {
        int idx = (bid - EBLK - TBLK) * 512 + t;
        if (idx >= N_ATOMS * 120) return;
        int i = idx / 120;
        int c = idx - i * 120;
        if (c >= 112) {
            ei0[(size_t)i * DINP0 + 376 + (c - 112)] = 0;
            return;
        }
        int s = sp[i];
        if (c < 16) {
            ei0[(size_t)i * DINP0 + c] = f2bf_rn(table[s * 16 + c]);
        } else {
            int cc = c - 16;
            float acc = 0.f;
#pragma unroll
            for (int k = 0; k < 16; k++)
                acc += table[s * 16 + k] * Wsi[k * 96 + cc];
            if (cc < 64) ei0[(size_t)i * DINP0 + 16 + cc] = f2bf_rn(acc);
            else         sd[i * 32 + cc - 64]             = acc;
        }
    } else {
        int e = (bid - EBLK - TBLK - S0BLK2) * 512 + t;
        if (e > NEA) return;
        if (e == NEA) {   // sentinel row: triplet pads index here -> dij = 0
            uint4 z = make_uint4(0, 0, 0, 0);
            *(uint4*)&dah0[(size_t)e * 8] = z;
            *(uint4*)&dah1[(size_t)e * 8] = z;
            return;
        }
        float d = dist[e];
        float s = sw2[e];
        float rb[8];
#pragma unroll
        for (int n = 0; n < 8; n++)
            rb[n] = 0.7559289460f * __sinf((n + 1) * 0.8975979010f * d) / d * s;
        unsigned short h0[8], h1[8];
#pragma unroll
        for (int c = 0; c < 8; c++) {
            float a0 = 0.f, a1 = 0.f;
#pragma unroll
            for (int n = 0; n < 8; n++) {
                a0 += rb[n] * Wda0[n * 8 + c];
                a1 += rb[n] * Wda1[n * 8 + c];
            }
            h0[c] = f2bf_rn(a0);
            h1[c] = f2bf_rn(a1);
        }
        *(uint4*)&dah0[e * 8] = *(uint4*)h0;
        *(uint4*)&dah1[e * 8] = *(uint4*)h1;
    }
}

// ------------------------------------------------------------------
// k_binB2: one workgroup per bucket. Per-atom PADDED bases within the
// bucket's padded region (fbase = bkoff[b] + b*PADB); writes
// ebase/epcnt (tbase/tpcnt); zero-fills pad slots; scatters.
// EDGES: rb[8] stored EDGE-MAJOR (two coalesced float4 stores/edge —
// r10's group-transposed 8x4B scatter cost ~10us here with no k_seg
// gain; k_seg distributes via shfl instead, measured-equal).
// ------------------------------------------------------------------
__global__ __launch_bounds__(256) void k_binB2(const int* __restrict__ ebkoff,
                                               const int* __restrict__ ebcnt,
                                               const float4* __restrict__ ebuk,
                                               float* __restrict__ erb,
                                               int* __restrict__ edi,
                                               int* __restrict__ ebase_g,
                                               int* __restrict__ epcnt_g,
                                               const int* __restrict__ tbkoff,
                                               const int* __restrict__ tbcnt,
                                               const float4* __restrict__ tbuk,
                                               float4* __restrict__ tpay,
                                               int* __restrict__ tbase_g,
                                               int* __restrict__ tpcnt_g) {
    bool isE = blockIdx.x < NBUK;
    int b = isE ? blockIdx.x : (blockIdx.x - NBUK);
    const int* bkoff = isE ? ebkoff : tbkoff;
    const int* bkcnt = isE ? ebcnt : tbcnt;
    const float4* buk = isE ? ebuk : tbuk;
    int* baseg = isE ? ebase_g : tbase_g;
    int* pcntg = isE ? epcnt_g : tpcnt_g;
    int lo = b * APB;
    int hi = min(lo + APB, N_ATOMS);
    int sbase = bkoff[b];
    int bc = bkcnt[b];
    int fb = sbase + b * PADB;   // padded final base of this bucket
    __shared__ int cntA[APB];
    __shared__ int abase[APB];
    __shared__ int cur[APB];
    int t = threadIdx.x;
    if (t < APB) cntA[t] = 0;
    __syncthreads();
    for (int p = sbase + t; p < sbase + bc; p += 256) {
        int a = __float_as_int(((const float*)(buk + p))[3]);
        atomicAdd(&cntA[a - lo], 1);
    }
    __syncthreads();
    if (t == 0) {
        int run = fb;
        for (int k = 0; k < hi - lo; k++) {
            int pc = (cntA[k] + 7) & ~7;
            abase[k] = run;
            cur[k] = run;
            baseg[lo + k] = run;
            pcntg[lo + k] = pc;
            run += pc;
        }
    }
    __syncthreads();
    // zero-fill pad slots
    if (t < hi - lo) {
        int c = cntA[t];
        int pc = (c + 7) & ~7;
        int base = abase[t];
        if (isE) {
            float4 z = make_float4(0.f, 0.f, 0.f, 0.f);
            for (int s = base + c; s < base + pc; s++) {
                edi[s] = 0;
                *(float4*)&erb[(size_t)s * 8]     = z;
                *(float4*)&erb[(size_t)s * 8 + 4] = z;
            }
        } else {
            float4 pz = make_float4(0.f, __int_as_float(NEA), __int_as_float(NEA), 0.f);
            for (int s = base + c; s < base + pc; s++) tpay[s] = pz;
        }
    }
    __syncthreads();
    for (int p = sbase + t; p < sbase + bc; p += 256) {
        float4 pay = buk[p];
        int a = __float_as_int(pay.w);
        int k = a - lo;
        int slot = atomicAdd(&cur[k], 1);
        if (isE) {
            float d = pay.x, s2 = pay.y;
            float q = 0.6324555320f * s2 / d;
            float r[8];
#pragma unroll
            for (int nn = 0; nn < 8; nn++)
                r[nn] = q * __sinf((nn + 1) * 0.6283185307f * d);
            *(float4*)&erb[(size_t)slot * 8]     = make_float4(r[0], r[1], r[2], r[3]);
            *(float4*)&erb[(size_t)slot * 8 + 4] = make_float4(r[4], r[5], r[6], r[7]);
            edi[slot] = __float_as_int(pay.z);
        } else {
            tpay[slot] = pay;
        }
    }
}

// ------------------------------------------------------------------
// layer 1 s: MFMA GEMM 25000x96 (ei1 bf16: A-staging is raw 16B copy)
// ------------------------------------------------------------------
__global__ __launch_bounds__(256) void k_s1(const unsigned short* __restrict__ ei1,
                                            const bf8* __restrict__ Wf,
                                            unsigned short* __restrict__ ei1o,
                                            float* __restrict__ sd) {
    __shared__ __align__(16) __bf16 Asg[4][64][8];
    int t = threadIdx.x;
    int w = t >> 6, lane = t & 63;
    int a0 = blockIdx.x * 64;

    int satom = a0 + (t >> 2);
    int k8 = (t & 3) * 8;
    const unsigned short* arow = &ei1[(size_t)satom * DINP1 + k8];
    bool aok = satom < N_ATOMS;
    int dw = (t >> 2) >> 4;
    int dl = ((t >> 2) & 15) | ((t & 3) << 4);
    __bf16* adst = &Asg[dw][dl][0];

    f4 acc[6];
#pragma unroll
    for (int j = 0; j < 6; j++) {
        f4 z = {0.f, 0.f, 0.f, 0.f};
        acc[j] = z;
    }

    for (int ch = 0; ch < 8; ch++) {
        uint4 v = make_uint4(0, 0, 0, 0);
        if (aok) v = *(const uint4*)(arow + ch * 32);
        __syncthreads();
        *(uint4*)adst = v;
        __syncthreads();
        bf8 afr = *(const bf8*)&Asg[w][lane][0];
        const bf8* wp = &Wf[(ch * 6) * 64 + lane];
#pragma unroll
        for (int tn = 0; tn < 6; tn++) {
            bf8 b = wp[tn * 64];
            acc[tn] = __builtin_amdgcn_mfma_f32_16x16x32_bf16(afr, b, acc[tn], 0, 0, 0);
        }
    }

    int nlo = lane & 15, q = lane >> 4;
#pragma unroll
    for (int r = 0; r < 4; r++) {
        int atom = a0 + w * 16 + q * 4 + r;
        if (atom < N_ATOMS) {
#pragma unroll
            for (int tn = 0; tn < 6; tn++) {
                int col = tn * 16 + nlo;
                float v = acc[tn][r];
                if (col < 64) ei1o[(size_t)atom * DINP1 + 256 + col] = f2bf_rn(v);
                else          sd[atom * 32 + col - 64] = v;
            }
        }
    }
    for (int z = t; z < 64 * 24; z += 256) {
        int za = a0 + z / 24;
        if (za < N_ATOMS) ei1o[(size_t)za * DINP1 + 616 + z % 24] = 0;
    }
}

// ------------------------------------------------------------------
// ami window helper: ALL dah gathers for the window (<=8 groups)
// issued UPFRONT in a fully-unrolled guarded loop (guards are
// wave-uniform; static indices keep arrays in registers — rule #20).
// Converts ~4 serial gather-chains per wave into 1. MASKLESS (pads
// are sentinel triplets -> dij = 0).
// ------------------------------------------------------------------
__device__ __forceinline__ void ami_win(const float4 twA, const unsigned short* __restrict__ dah,
                                        int gmax, int jj, int c,
                                        float& a0, float& a1, float& a2, float& a3, float& a4) {
    float scv[8];
    unsigned short dAv[8], dBv[8];
#pragma unroll
    for (int g = 0; g < 8; g++) {
        if (g < gmax) {
            int sl = g * 8 + jj;
            scv[g] = __shfl(twA.x, sl, 64);
            int ea = __float_as_int(__shfl(twA.y, sl, 64));
            int eb = __float_as_int(__shfl(twA.z, sl, 64));
            dAv[g] = dah[ea * 8 + c];
            dBv[g] = dah[eb * 8 + c];
        }
    }
#pragma unroll
    for (int g = 0; g < 8; g++) {
        if (g < gmax) {
            float dij = bf2f(dAv[g]) * bf2f(dBv[g]);
            float c1 = scv[g];
            float c2 = __builtin_fmaf(2.f * c1, c1, -1.f);
            float c3 = __builtin_fmaf(2.f * c1, c2, -c1);
            float c4 = __builtin_fmaf(2.f * c1, c3, -c2);
            a0 += dij;
            a1 = __builtin_fmaf(c1, dij, a1);
            a2 = __builtin_fmaf(c2, dij, a2);
            a3 = __builtin_fmaf(c3, dij, a3);
            a4 = __builtin_fmaf(c4, dij, a4);
        }
    }
}

// ------------------------------------------------------------------
// k_seg: 2 atoms/block, 2 waves/atom (r6-proven). ami blocks first
// (LPT). PADDED per-atom regions (maskless). mi: erb read coalesced
// (1 load covers the 8-edge group x 8 bases) + shfl distribution,
// with cross-group cA/cB prefetch.
// ------------------------------------------------------------------
__global__ __launch_bounds__(256) void k_seg(const int* __restrict__ ebase,
                                             const int* __restrict__ epcnt,
                                             const float* __restrict__ erb,
                                             const int* __restrict__ edi,
                                             const float* __restrict__ sd,
                                             unsigned short* __restrict__ mo, int mstride,
                                             const int* __restrict__ tbase,
                                             const int* __restrict__ tpcnt,
                                             const float4* __restrict__ tpay,
                                             const unsigned short* __restrict__ dah,
                                             unsigned short* __restrict__ ao, int astride) {
    __shared__ float4 smi[2][64];
    __shared__ float  sam[2][5][8];
    int t = threadIdx.x;
    int wv = t >> 6, l = t & 63;
    int slot = wv >> 1;
    int p    = wv & 1;

    if ((int)blockIdx.x < MIBLK) {
        // ---------------- ami ----------------
        int i = blockIdx.x * 2 + slot;
        bool valid = (i < N_ATOMS);
        int pbeg = 0, pcnt = 0;
        if (valid) { pbeg = tbase[i]; pcnt = tpcnt[i]; }
        int jj = l >> 3, c = l & 7;
        float a0 = 0.f, a1 = 0.f, a2 = 0.f, a3 = 0.f, a4 = 0.f;

        if (pcnt > 0) {
            int nG = pcnt >> 3;
            if (pcnt <= 128) {
                int h0 = (nG + 1) >> 1;
                int gb = p ? h0 : 0;
                int myg = p ? (nG - h0) : h0;
                if (myg > 0) {
                    int tb = gb * 8;
                    float4 twA = tpay[pbeg + tb + min(l, myg * 8 - 1)];
                    ami_win(twA, dah, myg, jj, c, a0, a1, a2, a3, a4);
                }
            } else {
                int nW = (pcnt + 63) >> 6;
                for (int W = p; W < nW; W += 2) {
                    int wbase = W * 64;
                    int rem = pcnt - wbase;
                    int lim = min(rem, 64);
                    float4 twA = tpay[pbeg + wbase + min(l, rem - 1)];
                    ami_win(twA, dah, lim >> 3, jj, c, a0, a1, a2, a3, a4);
                }
            }
        }

        // reduce over jj within wave (lanes l, l^8, l^16, l^32)
#pragma unroll
        for (int msk = 8; msk <= 32; msk <<= 1) {
            a0 += __shfl_xor(a0, msk, 64);
            a1 += __shfl_xor(a1, msk, 64);
            a2 += __shfl_xor(a2, msk, 64);
            a3 += __shfl_xor(a3, msk, 64);
            a4 += __shfl_xor(a4, msk, 64);
        }
        if (p == 1 && l < 8) {
            sam[slot][0][l] = a0; sam[slot][1][l] = a1; sam[slot][2][l] = a2;
            sam[slot][3][l] = a3; sam[slot][4][l] = a4;
        }
        __syncthreads();
        if (valid && p == 0 && l < 8) {
            a0 += sam[slot][0][l]; a1 += sam[slot][1][l]; a2 += sam[slot][2][l];
            a3 += sam[slot][3][l]; a4 += sam[slot][4][l];
            unsigned short* o = &ao[(size_t)i * astride + c];
            o[0]  = f2bf_rn(a0);
            o[8]  = f2bf_rn(a1);
            o[16] = f2bf_rn(a2);
            o[24] = f2bf_rn(a3);
            o[32] = f2bf_rn(a4);
        }
    } else {
        // ---------------- mi ----------------
        int i = ((int)blockIdx.x - MIBLK) * 2 + slot;
        bool valid = (i < N_ATOMS);
        int pbeg = 0, pcnt = 0;
        if (valid) { pbeg = ebase[i]; pcnt = epcnt[i]; }
        int n = l >> 3, cb = (l & 7) * 4;
        float4 acc = make_float4(0.f, 0.f, 0.f, 0.f);

        if (pcnt > 0) {
            int nG = pcnt >> 3;
            int h0 = (nG + 1) >> 1;
            int gbeg = p ? h0 : 0;
            int gend = p ? nG : h0;
            if (pcnt <= 64) {
                int eWin = edi[pbeg + min(l, pcnt - 1)];
                if (gbeg < gend) {
                    float cA = erb[((size_t)pbeg + gbeg * 8) * 8 + l];
                    for (int g = gbeg; g < gend; g++) {
                        float4 v[8];
#pragma unroll
                        for (int j = 0; j < 8; j++) {
                            int eid = __shfl(eWin, g * 8 + j, 64);
                            v[j] = *(const float4*)&sd[eid * 32 + cb];
                        }
                        float cB = 0.f;
                        if (g + 1 < gend) cB = erb[((size_t)pbeg + g * 8 + 8) * 8 + l];
#pragma unroll
                        for (int j = 0; j < 8; j++) {
                            float rbj = __shfl(cA, j * 8 + n, 64);
                            acc.x += rbj * v[j].x; acc.y += rbj * v[j].y;
                            acc.z += rbj * v[j].z; acc.w += rbj * v[j].w;
                        }
                        if (g + 1 < gend) cA = cB;
                    }
                }
            } else {
                const int* dp = edi + pbeg;
                for (int g = gbeg; g < gend; g++) {
                    const float* rp = erb + ((size_t)pbeg + g * 8) * 8 + n;
                    float4 v[8];
#pragma unroll
                    for (int j = 0; j < 8; j++) {
                        int eid = dp[g * 8 + j];
                        v[j] = *(const float4*)&sd[eid * 32 + cb];
                    }
#pragma unroll
                    for (int j = 0; j < 8; j++) {
                        float rbj = rp[j * 8];
                        acc.x += rbj * v[j].x; acc.y += rbj * v[j].y;
                        acc.z += rbj * v[j].z; acc.w += rbj * v[j].w;
                    }
                }
            }
        }

        if (p == 1) smi[slot][l] = acc;
        __syncthreads();
        if (valid && p == 0) {
            float4 o = smi[slot][l];
            acc.x += o.x; acc.y += o.y; acc.z += o.z; acc.w += o.w;
            ushort4 pk = make_ushort4(f2bf_rn(acc.x), f2bf_rn(acc.y),
                                      f2bf_rn(acc.z), f2bf_rn(acc.w));
            *(ushort4*)&mo[(size_t)i * mstride + l * 4] = pk;   // n*32+cb == l*4
        }
    }
}

// ------------------------------------------------------------------
// MFMA GEMM: dxi = tssr2(ei @ W + b). ei bf16 (raw 8B A-staging).
// LAYER 0 writes bf16 ei1; LAYER 1 writes fp32 out with bf16 skip.
// ------------------------------------------------------------------
template <int LAYER>
__global__ __launch_bounds__(256) void k_gemm(const unsigned short* __restrict__ ei,
                                              const bf8* __restrict__ Wf,
                                              const float* __restrict__ bias,
                                              const unsigned short* __restrict__ skip,
                                              float* __restrict__ outf,
                                              unsigned short* __restrict__ outb) {
    constexpr int DINP = (LAYER == 0) ? DINP0 : DINP1;
    constexpr int NCH = DINP / 32;
    __shared__ __align__(16) __bf16 Asg[2][64][8];
    int t = threadIdx.x;
    int w = t >> 6, lane = t & 63;
    int a0 = blockIdx.x * 32;

    int f  = t * 4;
    int tA = f >> 9;
    int al = (f >> 3) & 63;
    int j0 = f & 7;
    int sm = al & 15, sq = al >> 4;
    int ga = a0 + tA * 16 + sm;
    const unsigned short* arow = &ei[(size_t)ga * DINP + sq * 8 + j0];
    __bf16* adst = &Asg[0][0][0] + f;
    bool aok = (ga < N_ATOMS);

    f4 acc[2][4];
#pragma unroll
    for (int i = 0; i < 2; i++)
#pragma unroll
        for (int j = 0; j < 4; j++) {
            f4 z = {0.f, 0.f, 0.f, 0.f};
            acc[i][j] = z;
        }

    for (int ch = 0; ch < NCH; ch++) {
        uint2 v = make_uint2(0, 0);
        if (aok) v = *(const uint2*)(arow + ch * 32);
        __syncthreads();
        *(uint2*)adst = v;
        __syncthreads();
        bf8 afr0 = *(const bf8*)&Asg[0][lane][0];
        bf8 afr1 = *(const bf8*)&Asg[1][lane][0];
        const bf8* wp = &Wf[(ch * 16 + w * 4) * 64 + lane];
#pragma unroll
        for (int tn = 0; tn < 4; tn++) {
            bf8 b = wp[tn * 64];
            acc[0][tn] = __builtin_amdgcn_mfma_f32_16x16x32_bf16(afr0, b, acc[0][tn], 0, 0, 0);
            acc[1][tn] = __builtin_amdgcn_mfma_f32_16x16x32_bf16(afr1, b, acc[1][tn], 0, 0, 0);
        }
    }

    int nlo = lane & 15, q = lane >> 4;
#pragma unroll
    for (int tA2 = 0; tA2 < 2; tA2++) {
#pragma unroll
        for (int r = 0; r < 4; r++) {
            int atom = a0 + tA2 * 16 + q * 4 + r;
            if (atom < N_ATOMS) {
#pragma unroll
                for (int tn = 0; tn < 4; tn++) {
                    int col = w * 64 + tn * 16 + nlo;
                    float vv = tssr2f(acc[tA2][tn][r] + bias[col]);
                    if (LAYER == 0) {
                        outb[(size_t)atom * DINP1 + col] = f2bf_rn(vv);
                    } else {
                        outf[(size_t)atom * 256 + col] =
                            vv + bf2f(skip[(size_t)atom * DINP1 + col]);
                    }
                }
            }
        }
    }
}

// ------------------------------------------------------------------
extern "C" void kernel_launch(void* const* d_in, const int* in_sizes, int n_in,
                              void* d_out, int out_size, void* d_ws, size_t ws_size,
                              hipStream_t stream) {
    const int*   species     = (const int*)d_in[0];
    const int*   edge_src    = (const int*)d_in[1];
    const int*   edge_dst    = (const int*)d_in[2];
    const float* distances   = (const float*)d_in[3];
    const float* sw          = (const float*)d_in[4];
    const float* angles      = (const float*)d_in[5];
    const int*   angle_src   = (const int*)d_in[6];
    const int*   angle_dst   = (const int*)d_in[7];
    const int*   central     = (const int*)d_in[8];
    const float* dist_a      = (const float*)d_in[9];
    const float* sw_a        = (const float*)d_in[10];
    const float* table       = (const float*)d_in[11];
    const float* W_si0       = (const float*)d_in[12];
    const float* W_si1       = (const float*)d_in[13];
    const float* W_da0       = (const float*)d_in[14];
    const float* W_da1       = (const float*)d_in[15];
    const float* W_mix0      = (const float*)d_in[16];
    const float* b_mix0      = (const float*)d_in[17];
    const float* W_mix1      = (const float*)d_in[18];
    const float* b_mix1      = (const float*)d_in[19];
    float* out = (float*)d_out;

    char* p = (char*)d_ws;
    auto alloc = [&](size_t bytes) {
        char* r = p;
        p += (bytes + 255) & ~(size_t)255;
        return (void*)r;
    };
    unsigned short* ei0 = (unsigned short*)alloc((size_t)N_ATOMS * DINP0 * 2);
    unsigned short* ei1 = (unsigned short*)alloc((size_t)N_ATOMS * DINP1 * 2);
    float*  sd   = (float*)alloc((size_t)N_ATOMS * 32 * 4);
    unsigned short* dah0 = (unsigned short*)alloc((size_t)(NEA + 1) * 8 * 2);
    unsigned short* dah1 = (unsigned short*)alloc((size_t)(NEA + 1) * 8 * 2);
    float*  erbf = (float*)alloc((size_t)(NE + NBUK * PADB) * 8 * 4);
    int*    edi  = (int*)alloc((size_t)(NE + NBUK * PADB) * 4);
    float4* tpay = (float4*)alloc((size_t)(NT + NBUK * PADB) * 16);
    float4* ebuk = (float4*)alloc((size_t)NE * 16);
    bf8*    Wf0  = (bf8*)alloc((size_t)NFRAG0 * 16);
    bf8*    Wf1  = (bf8*)alloc((size_t)NFRAG1 * 16);
    bf8*    WfS1 = (bf8*)alloc((size_t)NFRAGS * 16);
    int* ebase  = (int*)alloc((size_t)N_ATOMS * 4);
    int* epcnt  = (int*)alloc((size_t)N_ATOMS * 4);
    int* tbase  = (int*)alloc((size_t)N_ATOMS * 4);
    int* tpcnt  = (int*)alloc((size_t)N_ATOMS * 4);
    int* bcnt   = (int*)alloc((size_t)2 * NBUK * 4);   // ebcnt | tbcnt (one memset)
    int* ebkoff = (int*)alloc((size_t)(NBUK + 1) * 4);
    int* tbkoff = (int*)alloc((size_t)(NBUK + 1) * 4);
    int* gce    = (int*)alloc((size_t)NBUK * 4);
    int* gct    = (int*)alloc((size_t)NBUK * 4);
    (void)ws_size;
    int* ebcnt = bcnt;
    int* tbcnt = bcnt + NBUK;

    // triplet staging aliases ei1 (consumed by k_binB2 before ei1 written)
    float4* tbuk = (float4*)ei1;

    hipMemsetAsync(bcnt, 0, (size_t)2 * NBUK * 4, stream);

    k_wc<<<WBLK + EBLK + TBLK, 256, 0, stream>>>(
        W_mix0, Wf0, W_mix1, Wf1, W_si1, WfS1,
        edge_src, central, ebcnt, tbcnt);

    k_scanB<<<2, 512, 0, stream>>>(ebcnt, ebkoff, gce, tbcnt, tbkoff, gct);

    k_bpre<<<EBLK + TBLK + S0BLK2 + DABLK2, 512, 0, stream>>>(
        distances, sw, edge_dst, edge_src, gce, ebuk,
        angles, angle_src, angle_dst, central, gct, tbuk,
        species, table, W_si0, ei0, sd,
        dist_a, sw_a, W_da0, W_da1, dah0, dah1);

    k_binB2<<<2 * NBUK, 256, 0, stream>>>(
        ebkoff, ebcnt, ebuk, erbf, edi, ebase, epcnt,
        tbkoff, tbcnt, tbuk, tpay, tbase, tpcnt);

    int gemm_grid = (N_ATOMS + 31) / 32;

    // ---- layer 0 ----
    k_seg<<<2 * MIBLK, 256, 0, stream>>>(ebase, epcnt, erbf, edi, sd, ei0 + 80, DINP0,
                                         tbase, tpcnt, tpay, dah0, ei0 + 336, DINP0);
    k_gemm<0><<<gemm_grid, 256, 0, stream>>>(ei0, Wf0, b_mix0, nullptr, nullptr, ei1);

    // ---- layer 1 ----
    k_s1<<<(N_ATOMS + 63) / 64, 256, 0, stream>>>(ei1, WfS1, ei1, sd);
    k_seg<<<2 * MIBLK, 256, 0, stream>>>(ebase, epcnt, erbf, edi, sd, ei1 + 320, DINP1,
                                         tbase, tpcnt, tpay, dah1, ei1 + 576, DINP1);
    k_gemm<1><<<gemm_grid, 256, 0, stream>>>(ei1, Wf1, b_mix1, ei1, out, nullptr);
}

// Round 12
// 373.640 us; speedup vs baseline: 1.4422x; 1.0732x over previous
//
#include <hip/hip_runtime.h>
#include <hip/hip_bf16.h>

typedef __hip_bfloat16 bf16;
typedef __bf16 bf8 __attribute__((ext_vector_type(8)));
typedef float  f4  __attribute__((ext_vector_type(4)));

#define N_ATOMS 25000
#define NE      800000
#define NEA     300000
#define NT      1600000
#define APB     64
#define NBUK    ((N_ATOMS + APB - 1) / APB)   // 391
#define PADB    512                            // per-bucket pad reservation (>= 64*7)

#define DIN0  376
#define DIN1  616
#define DINP0 384
#define DINP1 640

#define EBLK ((NE + 4095) / 4096)   // 196
#define TBLK ((NT + 4095) / 4096)   // 391

#define NFRAG0 ((DINP0 / 32) * 16 * 64)   // 12288
#define NFRAG1 ((DINP1 / 32) * 16 * 64)   // 20480
#define NFRAGS (8 * 6 * 64)               // 3072
#define WBLK   ((NFRAG0 + NFRAG1 + NFRAGS + 255) / 256)   // 140

#define S0BLK2 ((N_ATOMS * 120 + 511) / 512)   // 5860
#define DABLK2 ((NEA + 1 + 511) / 512)         // 587

#define MIBLK ((N_ATOMS + 1) / 2)   // 12500

__device__ __forceinline__ float tssr2f(float x) {
    float ax = fabsf(x);
    return (ax <= 1.f) ? x : copysignf(2.f * __builtin_sqrtf(ax) - 1.f, x);
}

__device__ __forceinline__ unsigned short f2bf_rn(float v) {
    unsigned int b = __float_as_uint(v);
    b += 0x7FFF + ((b >> 16) & 1);
    return (unsigned short)(b >> 16);
}
__device__ __forceinline__ float bf2f(unsigned short u) {
    return __uint_as_float(((unsigned int)u) << 16);
}

// ------------------------------------------------------------------
// k_wc (fused): blocks [0,WBLK) = W->bf16 fragment prep (3 matrices);
// rest = BUCKET-granularity counts via LDS histogram (r8-proven).
// ------------------------------------------------------------------
__device__ __forceinline__ void wprep_one(const float* __restrict__ W, bf8* __restrict__ Wf,
                                          int K, int N, int ntiles, int f) {
    int lane = f & 63;
    int ft = f >> 6;
    int tile = ft % ntiles;
    int chunk = ft / ntiles;
    int n = tile * 16 + (lane & 15);
    int kb = chunk * 32 + (lane >> 4) * 8;
    bf8 v;
#pragma unroll
    for (int j = 0; j < 8; j++) {
        int k = kb + j;
        v[j] = (__bf16)((k < K) ? W[k * N + n] : 0.f);
    }
    Wf[f] = v;
}

__global__ __launch_bounds__(256) void k_wc(const float* __restrict__ W0, bf8* __restrict__ Wf0,
                                            const float* __restrict__ W1, bf8* __restrict__ Wf1,
                                            const float* __restrict__ WS, bf8* __restrict__ WfS,
                                            const int* __restrict__ esrc, const int* __restrict__ cat,
                                            int* __restrict__ ebcnt, int* __restrict__ tbcnt) {
    int bid = blockIdx.x;
    int t = threadIdx.x;
    if (bid < WBLK) {
        int f = bid * 256 + t;
        if (f < NFRAG0) {
            wprep_one(W0, Wf0, DIN0, 256, 16, f);
        } else if (f < NFRAG0 + NFRAG1) {
            wprep_one(W1, Wf1, DIN1, 256, 16, f - NFRAG0);
        } else if (f < NFRAG0 + NFRAG1 + NFRAGS) {
            wprep_one(WS, WfS, 256, 96, 6, f - NFRAG0 - NFRAG1);
        }
        return;
    }
    bid -= WBLK;
    __shared__ int h[NBUK];
    for (int b = t; b < NBUK; b += 256) h[b] = 0;
    __syncthreads();
    bool isE = bid < EBLK;
    const int* key = isE ? esrc : cat;
    int n = isE ? NE : NT;
    int base = (isE ? bid : bid - EBLK) * 4096;
#pragma unroll
    for (int k = 0; k < 16; k++) {
        int idx = base + k * 256 + t;
        if (idx < n) atomicAdd(&h[key[idx] >> 6], 1);
    }
    __syncthreads();
    int* g = isE ? ebcnt : tbcnt;
    for (int b = t; b < NBUK; b += 256)
        if (h[b]) atomicAdd(&g[b], h[b]);
}

// ------------------------------------------------------------------
// k_scanB: scan 391 bucket counts -> compact staging bases (bkoff) and
// staging cursors (gcur). Padded base of bucket b = bkoff[b] + b*PADB.
// ------------------------------------------------------------------
__global__ __launch_bounds__(512) void k_scanB(const int* cnt0, int* off0, int* cur0,
                                               const int* cnt1, int* off1, int* cur1) {
    const int* cnt = blockIdx.x ? cnt1 : cnt0;
    int* off = blockIdx.x ? off1 : off0;
    int* cur = blockIdx.x ? cur1 : cur0;
    __shared__ int sh[512];
    int t = threadIdx.x;
    int v = (t < NBUK) ? cnt[t] : 0;
    sh[t] = v;
    __syncthreads();
    for (int d = 1; d < 512; d <<= 1) {
        int a = (t >= d) ? sh[t - d] : 0;
        __syncthreads();
        sh[t] += a;
        __syncthreads();
    }
    int excl = sh[t] - v;
    if (t <= NBUK) { off[t] = excl; if (t < NBUK) cur[t] = excl; }
}

// ------------------------------------------------------------------
// k_bpre (fused): phase-A binning; layer-0 species/si fill (bf16);
// da for BOTH layers INTERLEAVED: dah01[e*8+c] = h0|h1<<16 so one 4B
// gather in k_seg serves both layers (+ zero sentinel row at NEA).
// ------------------------------------------------------------------
__global__ __launch_bounds__(512) void k_bpre(const float* __restrict__ eA,
                                              const float* __restrict__ eB,
                                              const int* __restrict__ eC,
                                              const int* __restrict__ ekey,
                                              int* __restrict__ egcur,
                                              float4* __restrict__ ebuk,
                                              const float* __restrict__ tA,
                                              const int* __restrict__ tB,
                                              const int* __restrict__ tC,
                                              const int* __restrict__ tkey,
                                              int* __restrict__ tgcur,
                                              float4* __restrict__ tbuk,
                                              const int* __restrict__ sp,
                                              const float* __restrict__ table,
                                              const float* __restrict__ Wsi,
                                              unsigned short* __restrict__ ei0,
                                              float* __restrict__ sd,
                                              const float* __restrict__ dist,
                                              const float* __restrict__ sw2,
                                              const float* __restrict__ Wda0,
                                              const float* __restrict__ Wda1,
                                              unsigned* __restrict__ dah01) {
    int bid = blockIdx.x;
    int t = threadIdx.x;
    if (bid < EBLK + TBLK) {
        __shared__ int cnt[NBUK];
        __shared__ int rbase[NBUK];
        for (int b = t; b < NBUK; b += 512) cnt[b] = 0;
        __syncthreads();
        bool isE = bid < EBLK;
        const int* key = isE ? ekey : tkey;
        int n = isE ? NE : NT;
        int* gcur = isE ? egcur : tgcur;
        float4* buk = isE ? ebuk : tbuk;
        int base = (isE ? bid : (bid - EBLK)) * 4096;
        float4 pay[8];
        int bk[8], off[8];
#pragma unroll
        for (int k = 0; k < 8; k++) {
            int idx = base + k * 512 + t;
            bk[k] = -1;
            if (idx < n) {
                float4 p;
                if (isE) {
                    p.x = eA[idx];
                    p.y = eB[idx];
                    p.z = __int_as_float(eC[idx]);
                } else {
                    p.x = __cosf(tA[idx]);
                    p.y = __int_as_float(tB[idx]);
                    p.z = __int_as_float(tC[idx]);
                }
                int ky = key[idx];
                p.w = __int_as_float(ky);
                pay[k] = p;
                bk[k] = ky >> 6;
                off[k] = atomicAdd(&cnt[bk[k]], 1);
            }
        }
        __syncthreads();
        for (int b = t; b < NBUK; b += 512)
            if (cnt[b]) rbase[b] = atomicAdd(&gcur[b], cnt[b]);
        __syncthreads();
#pragma unroll
        for (int k = 0; k < 8; k++)
            if (bk[k] >= 0) buk[rbase[bk[k]] + off[k]] = pay[k];
    } else if (bid < EBLK + TBLK + S0BLK2) {
        int idx = (bid - EBLK - TBLK) * 512 + t;
        if (idx >= N_ATOMS * 120) return;
        int i = idx / 120;
        int c = idx - i * 120;
        if (c >= 112) {
            ei0[(size_t)i * DINP0 + 376 + (c - 112)] = 0;
            return;
        }
        int s = sp[i];
        if (c < 16) {
            ei0[(size_t)i * DINP0 + c] = f2bf_rn(table[s * 16 + c]);
        } else {
            int cc = c - 16;
            float acc = 0.f;
#pragma unroll
            for (int k = 0; k < 16; k++)
                acc += table[s * 16 + k] * Wsi[k * 96 + cc];
            if (cc < 64) ei0[(size_t)i * DINP0 + 16 + cc] = f2bf_rn(acc);
            else         sd[i * 32 + cc - 64]             = acc;
        }
    } else {
        int e = (bid - EBLK - TBLK - S0BLK2) * 512 + t;
        if (e > NEA) return;
        if (e == NEA) {   // sentinel row: triplet pads index here -> dij = 0
            uint4 z = make_uint4(0, 0, 0, 0);
            *(uint4*)&dah01[(size_t)e * 8]     = z;
            *(uint4*)&dah01[(size_t)e * 8 + 4] = z;
            return;
        }
        float d = dist[e];
        float s = sw2[e];
        float rb[8];
#pragma unroll
        for (int n = 0; n < 8; n++)
            rb[n] = 0.7559289460f * __sinf((n + 1) * 0.8975979010f * d) / d * s;
        unsigned u[8];
#pragma unroll
        for (int c = 0; c < 8; c++) {
            float a0 = 0.f, a1 = 0.f;
#pragma unroll
            for (int n = 0; n < 8; n++) {
                a0 += rb[n] * Wda0[n * 8 + c];
                a1 += rb[n] * Wda1[n * 8 + c];
            }
            u[c] = (unsigned)f2bf_rn(a0) | ((unsigned)f2bf_rn(a1) << 16);
        }
        *(uint4*)&dah01[e * 8]     = *(uint4*)&u[0];
        *(uint4*)&dah01[e * 8 + 4] = *(uint4*)&u[4];
    }
}

// ------------------------------------------------------------------
// k_binB2: one workgroup per bucket. Per-atom PADDED bases within the
// bucket's padded region; writes ebase/epcnt (tbase/tpcnt); zero-
// fills pads; scatters. EDGES: rb edge-major (r11). TRIPLETS: packed
// to 8B — w0 = ea|(eb<<19), w1 = (eb>>13)|(fx<<6) with fx = 26-bit
// fixed-point cos (error <= 3e-8, lossless-grade) — halves the tpay
// stream in k_seg and binB2's write.
// ------------------------------------------------------------------
__global__ __launch_bounds__(256) void k_binB2(const int* __restrict__ ebkoff,
                                               const int* __restrict__ ebcnt,
                                               const float4* __restrict__ ebuk,
                                               float* __restrict__ erb,
                                               int* __restrict__ edi,
                                               int* __restrict__ ebase_g,
                                               int* __restrict__ epcnt_g,
                                               const int* __restrict__ tbkoff,
                                               const int* __restrict__ tbcnt,
                                               const float4* __restrict__ tbuk,
                                               uint2* __restrict__ tpay,
                                               int* __restrict__ tbase_g,
                                               int* __restrict__ tpcnt_g) {
    bool isE = blockIdx.x < NBUK;
    int b = isE ? blockIdx.x : (blockIdx.x - NBUK);
    const int* bkoff = isE ? ebkoff : tbkoff;
    const int* bkcnt = isE ? ebcnt : tbcnt;
    const float4* buk = isE ? ebuk : tbuk;
    int* baseg = isE ? ebase_g : tbase_g;
    int* pcntg = isE ? epcnt_g : tpcnt_g;
    int lo = b * APB;
    int hi = min(lo + APB, N_ATOMS);
    int sbase = bkoff[b];
    int bc = bkcnt[b];
    int fb = sbase + b * PADB;   // padded final base of this bucket
    __shared__ int cntA[APB];
    __shared__ int abase[APB];
    __shared__ int cur[APB];
    int t = threadIdx.x;
    if (t < APB) cntA[t] = 0;
    __syncthreads();
    for (int p = sbase + t; p < sbase + bc; p += 256) {
        int a = __float_as_int(((const float*)(buk + p))[3]);
        atomicAdd(&cntA[a - lo], 1);
    }
    __syncthreads();
    if (t == 0) {
        int run = fb;
        for (int k = 0; k < hi - lo; k++) {
            int pc = (cntA[k] + 7) & ~7;
            abase[k] = run;
            cur[k] = run;
            baseg[lo + k] = run;
            pcntg[lo + k] = pc;
            run += pc;
        }
    }
    __syncthreads();
    // zero-fill pad slots
    if (t < hi - lo) {
        int c = cntA[t];
        int pc = (c + 7) & ~7;
        int base = abase[t];
        if (isE) {
            float4 z = make_float4(0.f, 0.f, 0.f, 0.f);
            for (int s = base + c; s < base + pc; s++) {
                edi[s] = 0;
                *(float4*)&erb[(size_t)s * 8]     = z;
                *(float4*)&erb[(size_t)s * 8 + 4] = z;
            }
        } else {
            uint2 pz = make_uint2((unsigned)NEA | ((unsigned)NEA << 19),
                                  ((unsigned)NEA >> 13));
            for (int s = base + c; s < base + pc; s++) tpay[s] = pz;
        }
    }
    __syncthreads();
    for (int p = sbase + t; p < sbase + bc; p += 256) {
        float4 pay = buk[p];
        int a = __float_as_int(pay.w);
        int k = a - lo;
        int slot = atomicAdd(&cur[k], 1);
        if (isE) {
            float d = pay.x, s2 = pay.y;
            float q = 0.6324555320f * s2 / d;
            float r[8];
#pragma unroll
            for (int nn = 0; nn < 8; nn++)
                r[nn] = q * __sinf((nn + 1) * 0.6283185307f * d);
            *(float4*)&erb[(size_t)slot * 8]     = make_float4(r[0], r[1], r[2], r[3]);
            *(float4*)&erb[(size_t)slot * 8 + 4] = make_float4(r[4], r[5], r[6], r[7]);
            edi[slot] = __float_as_int(pay.z);
        } else {
            unsigned ea = (unsigned)__float_as_int(pay.y);
            unsigned eb = (unsigned)__float_as_int(pay.z);
            int fx = __float2int_rn(pay.x * 16777216.f);
            uint2 pk;
            pk.x = ea | (eb << 19);
            pk.y = (eb >> 13) | ((unsigned)fx << 6);
            tpay[slot] = pk;
        }
    }
}

// ------------------------------------------------------------------
// layer 1 s: MFMA GEMM 25000x96 (ei1 bf16: A-staging is raw 16B copy)
// ------------------------------------------------------------------
__global__ __launch_bounds__(256) void k_s1(const unsigned short* __restrict__ ei1,
                                            const bf8* __restrict__ Wf,
                                            unsigned short* __restrict__ ei1o,
                                            float* __restrict__ sd) {
    __shared__ __align__(16) __bf16 Asg[4][64][8];
    int t = threadIdx.x;
    int w = t >> 6, lane = t & 63;
    int a0 = blockIdx.x * 64;

    int satom = a0 + (t >> 2);
    int k8 = (t & 3) * 8;
    const unsigned short* arow = &ei1[(size_t)satom * DINP1 + k8];
    bool aok = satom < N_ATOMS;
    int dw = (t >> 2) >> 4;
    int dl = ((t >> 2) & 15) | ((t & 3) << 4);
    __bf16* adst = &Asg[dw][dl][0];

    f4 acc[6];
#pragma unroll
    for (int j = 0; j < 6; j++) {
        f4 z = {0.f, 0.f, 0.f, 0.f};
        acc[j] = z;
    }

    for (int ch = 0; ch < 8; ch++) {
        uint4 v = make_uint4(0, 0, 0, 0);
        if (aok) v = *(const uint4*)(arow + ch * 32);
        __syncthreads();
        *(uint4*)adst = v;
        __syncthreads();
        bf8 afr = *(const bf8*)&Asg[w][lane][0];
        const bf8* wp = &Wf[(ch * 6) * 64 + lane];
#pragma unroll
        for (int tn = 0; tn < 6; tn++) {
            bf8 b = wp[tn * 64];
            acc[tn] = __builtin_amdgcn_mfma_f32_16x16x32_bf16(afr, b, acc[tn], 0, 0, 0);
        }
    }

    int nlo = lane & 15, q = lane >> 4;
#pragma unroll
    for (int r = 0; r < 4; r++) {
        int atom = a0 + w * 16 + q * 4 + r;
        if (atom < N_ATOMS) {
#pragma unroll
            for (int tn = 0; tn < 6; tn++) {
                int col = tn * 16 + nlo;
                float v = acc[tn][r];
                if (col < 64) ei1o[(size_t)atom * DINP1 + 256 + col] = f2bf_rn(v);
                else          sd[atom * 32 + col - 64] = v;
            }
        }
    }
    for (int z = t; z < 64 * 24; z += 256) {
        int za = a0 + z / 24;
        if (za < N_ATOMS) ei1o[(size_t)za * DINP1 + 616 + z % 24] = 0;
    }
}

// ------------------------------------------------------------------
// ami window helper — BOTH layers from one gather (dah01 interleaved).
// All gathers issued upfront (1 latency chain); maskless (pads are
// sentinel triplets -> dij = 0). Packed 8B window (2 shfl/slot).
// ------------------------------------------------------------------
__device__ __forceinline__ void ami_win2(const uint2 tw, const unsigned* __restrict__ dah01,
                                         int gmax, int jj, int c,
                                         float* A0, float* A1) {
    int fxv[8];
    unsigned wAv[8], wBv[8];
#pragma unroll
    for (int g = 0; g < 8; g++) {
        if (g < gmax) {
            int sl = g * 8 + jj;
            unsigned w0 = (unsigned)__shfl((int)tw.x, sl, 64);
            unsigned w1 = (unsigned)__shfl((int)tw.y, sl, 64);
            int ea = (int)(w0 & 0x7FFFFu);
            int eb = (int)((w0 >> 19) | ((w1 & 0x3Fu) << 13));
            fxv[g] = ((int)w1) >> 6;
            wAv[g] = dah01[ea * 8 + c];
            wBv[g] = dah01[eb * 8 + c];
        }
    }
#pragma unroll
    for (int g = 0; g < 8; g++) {
        if (g < gmax) {
            float c1 = (float)fxv[g] * 5.9604644775390625e-8f;
            float dij0 = __uint_as_float(wAv[g] << 16) * __uint_as_float(wBv[g] << 16);
            float dij1 = __uint_as_float(wAv[g] & 0xFFFF0000u) *
                         __uint_as_float(wBv[g] & 0xFFFF0000u);
            float c2 = __builtin_fmaf(2.f * c1, c1, -1.f);
            float c3 = __builtin_fmaf(2.f * c1, c2, -c1);
            float c4 = __builtin_fmaf(2.f * c1, c3, -c2);
            A0[0] += dij0;
            A0[1] = __builtin_fmaf(c1, dij0, A0[1]);
            A0[2] = __builtin_fmaf(c2, dij0, A0[2]);
            A0[3] = __builtin_fmaf(c3, dij0, A0[3]);
            A0[4] = __builtin_fmaf(c4, dij0, A0[4]);
            A1[0] += dij1;
            A1[1] = __builtin_fmaf(c1, dij1, A1[1]);
            A1[2] = __builtin_fmaf(c2, dij1, A1[2]);
            A1[3] = __builtin_fmaf(c3, dij1, A1[3]);
            A1[4] = __builtin_fmaf(c4, dij1, A1[4]);
        }
    }
}

// ------------------------------------------------------------------
// k_seg: blocks [0,amiCnt) = ami (BOTH layers in one pass: same
// gathers/stream as one layer; writes ao0 AND ao1); blocks
// [amiCnt, amiCnt+MIBLK) = mi for ONE layer. Layer-0 launch:
// amiCnt=MIBLK (ami first, LPT). Layer-1 launch: amiCnt=0 (mi only —
// the whole second ami pass is eliminated).
// 2 atoms/block, 2 waves/atom (r6-proven); LDS combine; maskless.
// ------------------------------------------------------------------
__global__ __launch_bounds__(256) void k_seg(const int* __restrict__ ebase,
                                             const int* __restrict__ epcnt,
                                             const float* __restrict__ erb,
                                             const int* __restrict__ edi,
                                             const float* __restrict__ sd,
                                             unsigned short* __restrict__ mo, int mstride,
                                             const int* __restrict__ tbase,
                                             const int* __restrict__ tpcnt,
                                             const uint2* __restrict__ tpay,
                                             const unsigned* __restrict__ dah01,
                                             unsigned short* __restrict__ ao0, int astride0,
                                             unsigned short* __restrict__ ao1, int astride1,
                                             int amiCnt) {
    __shared__ float4 smi[2][64];
    __shared__ float  sam[2][10][8];
    int t = threadIdx.x;
    int wv = t >> 6, l = t & 63;
    int slot = wv >> 1;
    int p    = wv & 1;

    if ((int)blockIdx.x < amiCnt) {
        // ---------------- ami (both layers) ----------------
        int i = blockIdx.x * 2 + slot;
        bool valid = (i < N_ATOMS);
        int pbeg = 0, pcnt = 0;
        if (valid) { pbeg = tbase[i]; pcnt = tpcnt[i]; }
        int jj = l >> 3, c = l & 7;
        float A0[5] = {0.f, 0.f, 0.f, 0.f, 0.f};
        float A1[5] = {0.f, 0.f, 0.f, 0.f, 0.f};

        if (pcnt > 0) {
            int nG = pcnt >> 3;
            if (pcnt <= 128) {
                int h0 = (nG + 1) >> 1;
                int gb = p ? h0 : 0;
                int myg = p ? (nG - h0) : h0;
                if (myg > 0) {
                    int tb = gb * 8;
                    uint2 twA = tpay[pbeg + tb + min(l, myg * 8 - 1)];
                    ami_win2(twA, dah01, myg, jj, c, A0, A1);
                }
            } else {
                int nW = (pcnt + 63) >> 6;
                for (int W = p; W < nW; W += 2) {
                    int wbase = W * 64;
                    int rem = pcnt - wbase;
                    int lim = min(rem, 64);
                    uint2 twA = tpay[pbeg + wbase + min(l, rem - 1)];
                    ami_win2(twA, dah01, lim >> 3, jj, c, A0, A1);
                }
            }
        }

        // reduce over jj within wave (lanes l, l^8, l^16, l^32)
#pragma unroll
        for (int msk = 8; msk <= 32; msk <<= 1) {
#pragma unroll
            for (int k = 0; k < 5; k++) {
                A0[k] += __shfl_xor(A0[k], msk, 64);
                A1[k] += __shfl_xor(A1[k], msk, 64);
            }
        }
        if (p == 1 && l < 8) {
#pragma unroll
            for (int k = 0; k < 5; k++) {
                sam[slot][k][l]     = A0[k];
                sam[slot][k + 5][l] = A1[k];
            }
        }
        __syncthreads();
        if (valid && p == 0 && l < 8) {
            unsigned short* o0 = &ao0[(size_t)i * astride0 + c];
            unsigned short* o1 = &ao1[(size_t)i * astride1 + c];
#pragma unroll
            for (int k = 0; k < 5; k++) {
                o0[k * 8] = f2bf_rn(A0[k] + sam[slot][k][l]);
                o1[k * 8] = f2bf_rn(A1[k] + sam[slot][k + 5][l]);
            }
        }
    } else {
        // ---------------- mi ----------------
        int i = ((int)blockIdx.x - amiCnt) * 2 + slot;
        bool valid = (i < N_ATOMS);
        int pbeg = 0, pcnt = 0;
        if (valid) { pbeg = ebase[i]; pcnt = epcnt[i]; }
        int n = l >> 3, cb = (l & 7) * 4;
        float4 acc = make_float4(0.f, 0.f, 0.f, 0.f);

        if (pcnt > 0) {
            int nG = pcnt >> 3;
            int h0 = (nG + 1) >> 1;
            int gbeg = p ? h0 : 0;
            int gend = p ? nG : h0;
            if (pcnt <= 64) {
                int eWin = edi[pbeg + min(l, pcnt - 1)];
                if (gbeg < gend) {
                    float cA = erb[((size_t)pbeg + gbeg * 8) * 8 + l];
                    for (int g = gbeg; g < gend; g++) {
                        float4 v[8];
#pragma unroll
                        for (int j = 0; j < 8; j++) {
                            int eid = __shfl(eWin, g * 8 + j, 64);
                            v[j] = *(const float4*)&sd[eid * 32 + cb];
                        }
                        float cB = 0.f;
                        if (g + 1 < gend) cB = erb[((size_t)pbeg + g * 8 + 8) * 8 + l];
#pragma unroll
                        for (int j = 0; j < 8; j++) {
                            float rbj = __shfl(cA, j * 8 + n, 64);
                            acc.x += rbj * v[j].x; acc.y += rbj * v[j].y;
                            acc.z += rbj * v[j].z; acc.w += rbj * v[j].w;
                        }
                        if (g + 1 < gend) cA = cB;
                    }
                }
            } else {
                const int* dp = edi + pbeg;
                for (int g = gbeg; g < gend; g++) {
                    const float* rp = erb + ((size_t)pbeg + g * 8) * 8 + n;
                    float4 v[8];
#pragma unroll
                    for (int j = 0; j < 8; j++) {
                        int eid = dp[g * 8 + j];
                        v[j] = *(const float4*)&sd[eid * 32 + cb];
                    }
#pragma unroll
                    for (int j = 0; j < 8; j++) {
                        float rbj = rp[j * 8];
                        acc.x += rbj * v[j].x; acc.y += rbj * v[j].y;
                        acc.z += rbj * v[j].z; acc.w += rbj * v[j].w;
                    }
                }
            }
        }

        if (p == 1) smi[slot][l] = acc;
        __syncthreads();
        if (valid && p == 0) {
            float4 o = smi[slot][l];
            acc.x += o.x; acc.y += o.y; acc.z += o.z; acc.w += o.w;
            ushort4 pk = make_ushort4(f2bf_rn(acc.x), f2bf_rn(acc.y),
                                      f2bf_rn(acc.z), f2bf_rn(acc.w));
            *(ushort4*)&mo[(size_t)i * mstride + l * 4] = pk;   // n*32+cb == l*4
        }
    }
}

// ------------------------------------------------------------------
// MFMA GEMM: dxi = tssr2(ei @ W + b). ei bf16 (raw 8B A-staging).
// LAYER 0 writes bf16 ei1 (cols [0,256) only — ami1's [576,616)
// written earlier by k_seg survives); LAYER 1 writes fp32 out.
// ------------------------------------------------------------------
template <int LAYER>
__global__ __launch_bounds__(256) void k_gemm(const unsigned short* __restrict__ ei,
                                              const bf8* __restrict__ Wf,
                                              const float* __restrict__ bias,
                                              const unsigned short* __restrict__ skip,
                                              float* __restrict__ outf,
                                              unsigned short* __restrict__ outb) {
    constexpr int DINP = (LAYER == 0) ? DINP0 : DINP1;
    constexpr int NCH = DINP / 32;
    __shared__ __align__(16) __bf16 Asg[2][64][8];
    int t = threadIdx.x;
    int w = t >> 6, lane = t & 63;
    int a0 = blockIdx.x * 32;

    int f  = t * 4;
    int tA = f >> 9;
    int al = (f >> 3) & 63;
    int j0 = f & 7;
    int sm = al & 15, sq = al >> 4;
    int ga = a0 + tA * 16 + sm;
    const unsigned short* arow = &ei[(size_t)ga * DINP + sq * 8 + j0];
    __bf16* adst = &Asg[0][0][0] + f;
    bool aok = (ga < N_ATOMS);

    f4 acc[2][4];
#pragma unroll
    for (int i = 0; i < 2; i++)
#pragma unroll
        for (int j = 0; j < 4; j++) {
            f4 z = {0.f, 0.f, 0.f, 0.f};
            acc[i][j] = z;
        }

    for (int ch = 0; ch < NCH; ch++) {
        uint2 v = make_uint2(0, 0);
        if (aok) v = *(const uint2*)(arow + ch * 32);
        __syncthreads();
        *(uint2*)adst = v;
        __syncthreads();
        bf8 afr0 = *(const bf8*)&Asg[0][lane][0];
        bf8 afr1 = *(const bf8*)&Asg[1][lane][0];
        const bf8* wp = &Wf[(ch * 16 + w * 4) * 64 + lane];
#pragma unroll
        for (int tn = 0; tn < 4; tn++) {
            bf8 b = wp[tn * 64];
            acc[0][tn] = __builtin_amdgcn_mfma_f32_16x16x32_bf16(afr0, b, acc[0][tn], 0, 0, 0);
            acc[1][tn] = __builtin_amdgcn_mfma_f32_16x16x32_bf16(afr1, b, acc[1][tn], 0, 0, 0);
        }
    }

    int nlo = lane & 15, q = lane >> 4;
#pragma unroll
    for (int tA2 = 0; tA2 < 2; tA2++) {
#pragma unroll
        for (int r = 0; r < 4; r++) {
            int atom = a0 + tA2 * 16 + q * 4 + r;
            if (atom < N_ATOMS) {
#pragma unroll
                for (int tn = 0; tn < 4; tn++) {
                    int col = w * 64 + tn * 16 + nlo;
                    float vv = tssr2f(acc[tA2][tn][r] + bias[col]);
                    if (LAYER == 0) {
                        outb[(size_t)atom * DINP1 + col] = f2bf_rn(vv);
                    } else {
                        outf[(size_t)atom * 256 + col] =
                            vv + bf2f(skip[(size_t)atom * DINP1 + col]);
                    }
                }
            }
        }
    }
}

// ------------------------------------------------------------------
extern "C" void kernel_launch(void* const* d_in, const int* in_sizes, int n_in,
                              void* d_out, int out_size, void* d_ws, size_t ws_size,
                              hipStream_t stream) {
    const int*   species     = (const int*)d_in[0];
    const int*   edge_src    = (const int*)d_in[1];
    const int*   edge_dst    = (const int*)d_in[2];
    const float* distances   = (const float*)d_in[3];
    const float* sw          = (const float*)d_in[4];
    const float* angles      = (const float*)d_in[5];
    const int*   angle_src   = (const int*)d_in[6];
    const int*   angle_dst   = (const int*)d_in[7];
    const int*   central     = (const int*)d_in[8];
    const float* dist_a      = (const float*)d_in[9];
    const float* sw_a        = (const float*)d_in[10];
    const float* table       = (const float*)d_in[11];
    const float* W_si0       = (const float*)d_in[12];
    const float* W_si1       = (const float*)d_in[13];
    const float* W_da0       = (const float*)d_in[14];
    const float* W_da1       = (const float*)d_in[15];
    const float* W_mix0      = (const float*)d_in[16];
    const float* b_mix0      = (const float*)d_in[17];
    const float* W_mix1      = (const float*)d_in[18];
    const float* b_mix1      = (const float*)d_in[19];
    float* out = (float*)d_out;

    char* p = (char*)d_ws;
    auto alloc = [&](size_t bytes) {
        char* r = p;
        p += (bytes + 255) & ~(size_t)255;
        return (void*)r;
    };
    unsigned short* ei0 = (unsigned short*)alloc((size_t)N_ATOMS * DINP0 * 2);
    unsigned short* ei1 = (unsigned short*)alloc((size_t)N_ATOMS * DINP1 * 2);
    float*  sd   = (float*)alloc((size_t)N_ATOMS * 32 * 4);
    unsigned* dah01 = (unsigned*)alloc((size_t)(NEA + 1) * 8 * 4);
    float*  erbf = (float*)alloc((size_t)(NE + NBUK * PADB) * 8 * 4);
    int*    edi  = (int*)alloc((size_t)(NE + NBUK * PADB) * 4);
    uint2*  tpay = (uint2*)alloc((size_t)(NT + NBUK * PADB) * 8);
    float4* ebuk = (float4*)alloc((size_t)NE * 16);
    bf8*    Wf0  = (bf8*)alloc((size_t)NFRAG0 * 16);
    bf8*    Wf1  = (bf8*)alloc((size_t)NFRAG1 * 16);
    bf8*    WfS1 = (bf8*)alloc((size_t)NFRAGS * 16);
    int* ebase  = (int*)alloc((size_t)N_ATOMS * 4);
    int* epcnt  = (int*)alloc((size_t)N_ATOMS * 4);
    int* tbase  = (int*)alloc((size_t)N_ATOMS * 4);
    int* tpcnt  = (int*)alloc((size_t)N_ATOMS * 4);
    int* bcnt   = (int*)alloc((size_t)2 * NBUK * 4);   // ebcnt | tbcnt (one memset)
    int* ebkoff = (int*)alloc((size_t)(NBUK + 1) * 4);
    int* tbkoff = (int*)alloc((size_t)(NBUK + 1) * 4);
    int* gce    = (int*)alloc((size_t)NBUK * 4);
    int* gct    = (int*)alloc((size_t)NBUK * 4);
    (void)ws_size;
    int* ebcnt = bcnt;
    int* tbcnt = bcnt + NBUK;

    // triplet staging aliases ei1 (consumed by k_binB2 before ei1 written;
    // k_seg L0's ami1 write to ei1+576 happens AFTER k_binB2)
    float4* tbuk = (float4*)ei1;

    hipMemsetAsync(bcnt, 0, (size_t)2 * NBUK * 4, stream);

    k_wc<<<WBLK + EBLK + TBLK, 256, 0, stream>>>(
        W_mix0, Wf0, W_mix1, Wf1, W_si1, WfS1,
        edge_src, central, ebcnt, tbcnt);

    k_scanB<<<2, 512, 0, stream>>>(ebcnt, ebkoff, gce, tbcnt, tbkoff, gct);

    k_bpre<<<EBLK + TBLK + S0BLK2 + DABLK2, 512, 0, stream>>>(
        distances, sw, edge_dst, edge_src, gce, ebuk,
        angles, angle_src, angle_dst, central, gct, tbuk,
        species, table, W_si0, ei0, sd,
        dist_a, sw_a, W_da0, W_da1, dah01);

    k_binB2<<<2 * NBUK, 256, 0, stream>>>(
        ebkoff, ebcnt, ebuk, erbf, edi, ebase, epcnt,
        tbkoff, tbcnt, tbuk, tpay, tbase, tpcnt);

    int gemm_grid = (N_ATOMS + 31) / 32;

    // ---- layer 0 (ami computes BOTH layers' angular term) ----
    k_seg<<<2 * MIBLK, 256, 0, stream>>>(ebase, epcnt, erbf, edi, sd, ei0 + 80, DINP0,
                                         tbase, tpcnt, tpay, dah01,
                                         ei0 + 336, DINP0, ei1 + 576, DINP1, MIBLK);
    k_gemm<0><<<gemm_grid, 256, 0, stream>>>(ei0, Wf0, b_mix0, nullptr, nullptr, ei1);

    // ---- layer 1 (mi only; ami1 already in ei1+576) ----
    k_s1<<<(N_ATOMS + 63) / 64, 256, 0, stream>>>(ei1, WfS1, ei1, sd);
    k_seg<<<MIBLK, 256, 0, stream>>>(ebase, epcnt, erbf, edi, sd, ei1 + 320, DINP1,
                                     tbase, tpcnt, tpay, dah01,
                                     ei1 + 576, DINP1, ei1 + 576, DINP1, 0);
    k_gemm<1><<<gemm_grid, 256, 0, stream>>>(ei1, Wf1, b_mix1, ei1, out, nullptr);
}

// Round 13
// 364.988 us; speedup vs baseline: 1.4764x; 1.0237x over previous
//
#include <hip/hip_runtime.h>
#include <hip/hip_bf16.h>

typedef __hip_bfloat16 bf16;
typedef __bf16 bf8 __attribute__((ext_vector_type(8)));
typedef float  f4  __attribute__((ext_vector_type(4)));

#define N_ATOMS 25000
#define NE      800000
#define NEA     300000
#define NT      1600000
#define APB     64
#define NBUK    ((N_ATOMS + APB - 1) / APB)   // 391
#define PADB    512                            // per-bucket pad reservation (>= 64*7)

#define DIN0  376
#define DIN1  616
#define DINP0 384
#define DINP1 640

#define EBLK ((NE + 4095) / 4096)   // 196
#define TBLK ((NT + 4095) / 4096)   // 391

#define NFRAG0 ((DINP0 / 32) * 16 * 64)   // 12288
#define NFRAG1 ((DINP1 / 32) * 16 * 64)   // 20480
#define NFRAGS (8 * 6 * 64)               // 3072
#define WBLK   ((NFRAG0 + NFRAG1 + NFRAGS + 255) / 256)   // 140

#define S0BLK2 ((N_ATOMS * 120 + 511) / 512)   // 5860
#define DABLK2 ((NEA + 1 + 511) / 512)         // 587

#define MIBLK ((N_ATOMS + 1) / 2)   // 12500

__device__ __forceinline__ float tssr2f(float x) {
    float ax = fabsf(x);
    return (ax <= 1.f) ? x : copysignf(2.f * __builtin_sqrtf(ax) - 1.f, x);
}

__device__ __forceinline__ unsigned short f2bf_rn(float v) {
    unsigned int b = __float_as_uint(v);
    b += 0x7FFF + ((b >> 16) & 1);
    return (unsigned short)(b >> 16);
}
__device__ __forceinline__ float bf2f(unsigned short u) {
    return __uint_as_float(((unsigned int)u) << 16);
}

// ------------------------------------------------------------------
// k_wc (fused): blocks [0,WBLK) = W->bf16 fragment prep (3 matrices);
// rest = BUCKET-granularity counts via LDS histogram (r8-proven).
// ------------------------------------------------------------------
__device__ __forceinline__ void wprep_one(const float* __restrict__ W, bf8* __restrict__ Wf,
                                          int K, int N, int ntiles, int f) {
    int lane = f & 63;
    int ft = f >> 6;
    int tile = ft % ntiles;
    int chunk = ft / ntiles;
    int n = tile * 16 + (lane & 15);
    int kb = chunk * 32 + (lane >> 4) * 8;
    bf8 v;
#pragma unroll
    for (int j = 0; j < 8; j++) {
        int k = kb + j;
        v[j] = (__bf16)((k < K) ? W[k * N + n] : 0.f);
    }
    Wf[f] = v;
}

__global__ __launch_bounds__(256) void k_wc(const float* __restrict__ W0, bf8* __restrict__ Wf0,
                                            const float* __restrict__ W1, bf8* __restrict__ Wf1,
                                            const float* __restrict__ WS, bf8* __restrict__ WfS,
                                            const int* __restrict__ esrc, const int* __restrict__ cat,
                                            int* __restrict__ ebcnt, int* __restrict__ tbcnt) {
    int bid = blockIdx.x;
    int t = threadIdx.x;
    if (bid < WBLK) {
        int f = bid * 256 + t;
        if (f < NFRAG0) {
            wprep_one(W0, Wf0, DIN0, 256, 16, f);
        } else if (f < NFRAG0 + NFRAG1) {
            wprep_one(W1, Wf1, DIN1, 256, 16, f - NFRAG0);
        } else if (f < NFRAG0 + NFRAG1 + NFRAGS) {
            wprep_one(WS, WfS, 256, 96, 6, f - NFRAG0 - NFRAG1);
        }
        return;
    }
    bid -= WBLK;
    __shared__ int h[NBUK];
    for (int b = t; b < NBUK; b += 256) h[b] = 0;
    __syncthreads();
    bool isE = bid < EBLK;
    const int* key = isE ? esrc : cat;
    int n = isE ? NE : NT;
    int base = (isE ? bid : bid - EBLK) * 4096;
#pragma unroll
    for (int k = 0; k < 16; k++) {
        int idx = base + k * 256 + t;
        if (idx < n) atomicAdd(&h[key[idx] >> 6], 1);
    }
    __syncthreads();
    int* g = isE ? ebcnt : tbcnt;
    for (int b = t; b < NBUK; b += 256)
        if (h[b]) atomicAdd(&g[b], h[b]);
}

// ------------------------------------------------------------------
// k_scanB: scan 391 bucket counts -> compact staging bases (bkoff) and
// staging cursors (gcur). Padded base of bucket b = bkoff[b] + b*PADB.
// ------------------------------------------------------------------
__global__ __launch_bounds__(512) void k_scanB(const int* cnt0, int* off0, int* cur0,
                                               const int* cnt1, int* off1, int* cur1) {
    const int* cnt = blockIdx.x ? cnt1 : cnt0;
    int* off = blockIdx.x ? off1 : off0;
    int* cur = blockIdx.x ? cur1 : cur0;
    __shared__ int sh[512];
    int t = threadIdx.x;
    int v = (t < NBUK) ? cnt[t] : 0;
    sh[t] = v;
    __syncthreads();
    for (int d = 1; d < 512; d <<= 1) {
        int a = (t >= d) ? sh[t - d] : 0;
        __syncthreads();
        sh[t] += a;
        __syncthreads();
    }
    int excl = sh[t] - v;
    if (t <= NBUK) { off[t] = excl; if (t < NBUK) cur[t] = excl; }
}

// ------------------------------------------------------------------
// k_bpre (fused): phase-A binning; layer-0 species/si fill (bf16);
// da for BOTH layers INTERLEAVED: dah01[e*8+c] = h0|h1<<16 so one 4B
// gather in k_seg serves both layers (+ zero sentinel row at NEA).
// ------------------------------------------------------------------
__global__ __launch_bounds__(512) void k_bpre(const float* __restrict__ eA,
                                              const float* __restrict__ eB,
                                              const int* __restrict__ eC,
                                              const int* __restrict__ ekey,
                                              int* __restrict__ egcur,
                                              float4* __restrict__ ebuk,
                                              const float* __restrict__ tA,
                                              const int* __restrict__ tB,
                                              const int* __restrict__ tC,
                                              const int* __restrict__ tkey,
                                              int* __restrict__ tgcur,
                                              float4* __restrict__ tbuk,
                                              const int* __restrict__ sp,
                                              const float* __restrict__ table,
                                              const float* __restrict__ Wsi,
                                              unsigned short* __restrict__ ei0,
                                              float* __restrict__ sd,
                                              const float* __restrict__ dist,
                                              const float* __restrict__ sw2,
                                              const float* __restrict__ Wda0,
                                              const float* __restrict__ Wda1,
                                              unsigned* __restrict__ dah01) {
    int bid = blockIdx.x;
    int t = threadIdx.x;
    if (bid < EBLK + TBLK) {
        __shared__ int cnt[NBUK];
        __shared__ int rbase[NBUK];
        for (int b = t; b < NBUK; b += 512) cnt[b] = 0;
        __syncthreads();
        bool isE = bid < EBLK;
        const int* key = isE ? ekey : tkey;
        int n = isE ? NE : NT;
        int* gcur = isE ? egcur : tgcur;
        float4* buk = isE ? ebuk : tbuk;
        int base = (isE ? bid : (bid - EBLK)) * 4096;
        float4 pay[8];
        int bk[8], off[8];
#pragma unroll
        for (int k = 0; k < 8; k++) {
            int idx = base + k * 512 + t;
            bk[k] = -1;
            if (idx < n) {
                float4 p;
                if (isE) {
                    p.x = eA[idx];
                    p.y = eB[idx];
                    p.z = __int_as_float(eC[idx]);
                } else {
                    p.x = __cosf(tA[idx]);
                    p.y = __int_as_float(tB[idx]);
                    p.z = __int_as_float(tC[idx]);
                }
                int ky = key[idx];
                p.w = __int_as_float(ky);
                pay[k] = p;
                bk[k] = ky >> 6;
                off[k] = atomicAdd(&cnt[bk[k]], 1);
            }
        }
        __syncthreads();
        for (int b = t; b < NBUK; b += 512)
            if (cnt[b]) rbase[b] = atomicAdd(&gcur[b], cnt[b]);
        __syncthreads();
#pragma unroll
        for (int k = 0; k < 8; k++)
            if (bk[k] >= 0) buk[rbase[bk[k]] + off[k]] = pay[k];
    } else if (bid < EBLK + TBLK + S0BLK2) {
        int idx = (bid - EBLK - TBLK) * 512 + t;
        if (idx >= N_ATOMS * 120) return;
        int i = idx / 120;
        int c = idx - i * 120;
        if (c >= 112) {
            ei0[(size_t)i * DINP0 + 376 + (c - 112)] = 0;
            return;
        }
        int s = sp[i];
        if (c < 16) {
            ei0[(size_t)i * DINP0 + c] = f2bf_rn(table[s * 16 + c]);
        } else {
            int cc = c - 16;
            float acc = 0.f;
#pragma unroll
            for (int k = 0; k < 16; k++)
                acc += table[s * 16 + k] * Wsi[k * 96 + cc];
            if (cc < 64) ei0[(size_t)i * DINP0 + 16 + cc] = f2bf_rn(acc);
            else         sd[i * 32 + cc - 64]             = acc;
        }
    } else {
        int e = (bid - EBLK - TBLK - S0BLK2) * 512 + t;
        if (e > NEA) return;
        if (e == NEA) {   // sentinel row: triplet pads index here -> dij = 0
            uint4 z = make_uint4(0, 0, 0, 0);
            *(uint4*)&dah01[(size_t)e * 8]     = z;
            *(uint4*)&dah01[(size_t)e * 8 + 4] = z;
            return;
        }
        float d = dist[e];
        float s = sw2[e];
        float rb[8];
#pragma unroll
        for (int n = 0; n < 8; n++)
            rb[n] = 0.7559289460f * __sinf((n + 1) * 0.8975979010f * d) / d * s;
        unsigned u[8];
#pragma unroll
        for (int c = 0; c < 8; c++) {
            float a0 = 0.f, a1 = 0.f;
#pragma unroll
            for (int n = 0; n < 8; n++) {
                a0 += rb[n] * Wda0[n * 8 + c];
                a1 += rb[n] * Wda1[n * 8 + c];
            }
            u[c] = (unsigned)f2bf_rn(a0) | ((unsigned)f2bf_rn(a1) << 16);
        }
        *(uint4*)&dah01[e * 8]     = *(uint4*)&u[0];
        *(uint4*)&dah01[e * 8 + 4] = *(uint4*)&u[4];
    }
}

// ------------------------------------------------------------------
// k_binB2: one workgroup per bucket. Per-atom PADDED bases; writes
// ebase/epcnt (tbase/tpcnt); zero-fills pads; scatters.
// EDGES: rb[8] stored edge-major as BF16 (one 16B uint4 store/edge —
// halves the erb stream read twice by k_seg and written here).
// TRIPLETS: packed 8B (ea|eb|26-bit fixed-point cos).
// ------------------------------------------------------------------
__global__ __launch_bounds__(256) void k_binB2(const int* __restrict__ ebkoff,
                                               const int* __restrict__ ebcnt,
                                               const float4* __restrict__ ebuk,
                                               unsigned short* __restrict__ erb,
                                               int* __restrict__ edi,
                                               int* __restrict__ ebase_g,
                                               int* __restrict__ epcnt_g,
                                               const int* __restrict__ tbkoff,
                                               const int* __restrict__ tbcnt,
                                               const float4* __restrict__ tbuk,
                                               uint2* __restrict__ tpay,
                                               int* __restrict__ tbase_g,
                                               int* __restrict__ tpcnt_g) {
    bool isE = blockIdx.x < NBUK;
    int b = isE ? blockIdx.x : (blockIdx.x - NBUK);
    const int* bkoff = isE ? ebkoff : tbkoff;
    const int* bkcnt = isE ? ebcnt : tbcnt;
    const float4* buk = isE ? ebuk : tbuk;
    int* baseg = isE ? ebase_g : tbase_g;
    int* pcntg = isE ? epcnt_g : tpcnt_g;
    int lo = b * APB;
    int hi = min(lo + APB, N_ATOMS);
    int sbase = bkoff[b];
    int bc = bkcnt[b];
    int fb = sbase + b * PADB;   // padded final base of this bucket
    __shared__ int cntA[APB];
    __shared__ int abase[APB];
    __shared__ int cur[APB];
    int t = threadIdx.x;
    if (t < APB) cntA[t] = 0;
    __syncthreads();
    for (int p = sbase + t; p < sbase + bc; p += 256) {
        int a = __float_as_int(((const float*)(buk + p))[3]);
        atomicAdd(&cntA[a - lo], 1);
    }
    __syncthreads();
    if (t == 0) {
        int run = fb;
        for (int k = 0; k < hi - lo; k++) {
            int pc = (cntA[k] + 7) & ~7;
            abase[k] = run;
            cur[k] = run;
            baseg[lo + k] = run;
            pcntg[lo + k] = pc;
            run += pc;
        }
    }
    __syncthreads();
    // zero-fill pad slots
    if (t < hi - lo) {
        int c = cntA[t];
        int pc = (c + 7) & ~7;
        int base = abase[t];
        if (isE) {
            uint4 z4 = make_uint4(0, 0, 0, 0);
            for (int s = base + c; s < base + pc; s++) {
                edi[s] = 0;
                *(uint4*)&erb[(size_t)s * 8] = z4;
            }
        } else {
            uint2 pz = make_uint2((unsigned)NEA | ((unsigned)NEA << 19),
                                  ((unsigned)NEA >> 13));
            for (int s = base + c; s < base + pc; s++) tpay[s] = pz;
        }
    }
    __syncthreads();
    for (int p = sbase + t; p < sbase + bc; p += 256) {
        float4 pay = buk[p];
        int a = __float_as_int(pay.w);
        int k = a - lo;
        int slot = atomicAdd(&cur[k], 1);
        if (isE) {
            float d = pay.x, s2 = pay.y;
            float q = 0.6324555320f * s2 / d;
            unsigned short h[8];
#pragma unroll
            for (int nn = 0; nn < 8; nn++)
                h[nn] = f2bf_rn(q * __sinf((nn + 1) * 0.6283185307f * d));
            *(uint4*)&erb[(size_t)slot * 8] = *(uint4*)h;
            edi[slot] = __float_as_int(pay.z);
        } else {
            unsigned ea = (unsigned)__float_as_int(pay.y);
            unsigned eb = (unsigned)__float_as_int(pay.z);
            int fx = __float2int_rn(pay.x * 16777216.f);
            uint2 pk;
            pk.x = ea | (eb << 19);
            pk.y = (eb >> 13) | ((unsigned)fx << 6);
            tpay[slot] = pk;
        }
    }
}

// ------------------------------------------------------------------
// layer 1 s: MFMA GEMM 25000x96 (ei1 bf16: A-staging is raw 16B copy)
// ------------------------------------------------------------------
__global__ __launch_bounds__(256) void k_s1(const unsigned short* __restrict__ ei1,
                                            const bf8* __restrict__ Wf,
                                            unsigned short* __restrict__ ei1o,
                                            float* __restrict__ sd) {
    __shared__ __align__(16) __bf16 Asg[4][64][8];
    int t = threadIdx.x;
    int w = t >> 6, lane = t & 63;
    int a0 = blockIdx.x * 64;

    int satom = a0 + (t >> 2);
    int k8 = (t & 3) * 8;
    const unsigned short* arow = &ei1[(size_t)satom * DINP1 + k8];
    bool aok = satom < N_ATOMS;
    int dw = (t >> 2) >> 4;
    int dl = ((t >> 2) & 15) | ((t & 3) << 4);
    __bf16* adst = &Asg[dw][dl][0];

    f4 acc[6];
#pragma unroll
    for (int j = 0; j < 6; j++) {
        f4 z = {0.f, 0.f, 0.f, 0.f};
        acc[j] = z;
    }

    for (int ch = 0; ch < 8; ch++) {
        uint4 v = make_uint4(0, 0, 0, 0);
        if (aok) v = *(const uint4*)(arow + ch * 32);
        __syncthreads();
        *(uint4*)adst = v;
        __syncthreads();
        bf8 afr = *(const bf8*)&Asg[w][lane][0];
        const bf8* wp = &Wf[(ch * 6) * 64 + lane];
#pragma unroll
        for (int tn = 0; tn < 6; tn++) {
            bf8 b = wp[tn * 64];
            acc[tn] = __builtin_amdgcn_mfma_f32_16x16x32_bf16(afr, b, acc[tn], 0, 0, 0);
        }
    }

    int nlo = lane & 15, q = lane >> 4;
#pragma unroll
    for (int r = 0; r < 4; r++) {
        int atom = a0 + w * 16 + q * 4 + r;
        if (atom < N_ATOMS) {
#pragma unroll
            for (int tn = 0; tn < 6; tn++) {
                int col = tn * 16 + nlo;
                float v = acc[tn][r];
                if (col < 64) ei1o[(size_t)atom * DINP1 + 256 + col] = f2bf_rn(v);
                else          sd[atom * 32 + col - 64] = v;
            }
        }
    }
    for (int z = t; z < 64 * 24; z += 256) {
        int za = a0 + z / 24;
        if (za < N_ATOMS) ei1o[(size_t)za * DINP1 + 616 + z % 24] = 0;
    }
}

// ------------------------------------------------------------------
// ami window helper — BOTH layers from one gather (dah01 interleaved).
// All gathers issued upfront (1 latency chain); maskless (pads are
// sentinel triplets -> dij = 0). Packed 8B window (2 shfl/slot).
// ------------------------------------------------------------------
__device__ __forceinline__ void ami_win2(const uint2 tw, const unsigned* __restrict__ dah01,
                                         int gmax, int jj, int c,
                                         float* A0, float* A1) {
    int fxv[8];
    unsigned wAv[8], wBv[8];
#pragma unroll
    for (int g = 0; g < 8; g++) {
        if (g < gmax) {
            int sl = g * 8 + jj;
            unsigned w0 = (unsigned)__shfl((int)tw.x, sl, 64);
            unsigned w1 = (unsigned)__shfl((int)tw.y, sl, 64);
            int ea = (int)(w0 & 0x7FFFFu);
            int eb = (int)((w0 >> 19) | ((w1 & 0x3Fu) << 13));
            fxv[g] = ((int)w1) >> 6;
            wAv[g] = dah01[ea * 8 + c];
            wBv[g] = dah01[eb * 8 + c];
        }
    }
#pragma unroll
    for (int g = 0; g < 8; g++) {
        if (g < gmax) {
            float c1 = (float)fxv[g] * 5.9604644775390625e-8f;
            float dij0 = __uint_as_float(wAv[g] << 16) * __uint_as_float(wBv[g] << 16);
            float dij1 = __uint_as_float(wAv[g] & 0xFFFF0000u) *
                         __uint_as_float(wBv[g] & 0xFFFF0000u);
            float c2 = __builtin_fmaf(2.f * c1, c1, -1.f);
            float c3 = __builtin_fmaf(2.f * c1, c2, -c1);
            float c4 = __builtin_fmaf(2.f * c1, c3, -c2);
            A0[0] += dij0;
            A0[1] = __builtin_fmaf(c1, dij0, A0[1]);
            A0[2] = __builtin_fmaf(c2, dij0, A0[2]);
            A0[3] = __builtin_fmaf(c3, dij0, A0[3]);
            A0[4] = __builtin_fmaf(c4, dij0, A0[4]);
            A1[0] += dij1;
            A1[1] = __builtin_fmaf(c1, dij1, A1[1]);
            A1[2] = __builtin_fmaf(c2, dij1, A1[2]);
            A1[3] = __builtin_fmaf(c3, dij1, A1[3]);
            A1[4] = __builtin_fmaf(c4, dij1, A1[4]);
        }
    }
}

// ------------------------------------------------------------------
// k_seg: blocks [0,amiCnt) = ami (BOTH layers in one pass); blocks
// [amiCnt, amiCnt+MIBLK) = mi for ONE layer. L0: amiCnt=MIBLK.
// L1: amiCnt=0 (mi only). 2 atoms/block, 2 waves/atom; LDS combine;
// maskless. erb is BF16 (shfl as int, convert after shuffle).
// ------------------------------------------------------------------
__global__ __launch_bounds__(256) void k_seg(const int* __restrict__ ebase,
                                             const int* __restrict__ epcnt,
                                             const unsigned short* __restrict__ erb,
                                             const int* __restrict__ edi,
                                             const float* __restrict__ sd,
                                             unsigned short* __restrict__ mo, int mstride,
                                             const int* __restrict__ tbase,
                                             const int* __restrict__ tpcnt,
                                             const uint2* __restrict__ tpay,
                                             const unsigned* __restrict__ dah01,
                                             unsigned short* __restrict__ ao0, int astride0,
                                             unsigned short* __restrict__ ao1, int astride1,
                                             int amiCnt) {
    __shared__ float4 smi[2][64];
    __shared__ float  sam[2][10][8];
    int t = threadIdx.x;
    int wv = t >> 6, l = t & 63;
    int slot = wv >> 1;
    int p    = wv & 1;

    if ((int)blockIdx.x < amiCnt) {
        // ---------------- ami (both layers) ----------------
        int i = blockIdx.x * 2 + slot;
        bool valid = (i < N_ATOMS);
        int pbeg = 0, pcnt = 0;
        if (valid) { pbeg = tbase[i]; pcnt = tpcnt[i]; }
        int jj = l >> 3, c = l & 7;
        float A0[5] = {0.f, 0.f, 0.f, 0.f, 0.f};
        float A1[5] = {0.f, 0.f, 0.f, 0.f, 0.f};

        if (pcnt > 0) {
            int nG = pcnt >> 3;
            if (pcnt <= 128) {
                int h0 = (nG + 1) >> 1;
                int gb = p ? h0 : 0;
                int myg = p ? (nG - h0) : h0;
                if (myg > 0) {
                    int tb = gb * 8;
                    uint2 twA = tpay[pbeg + tb + min(l, myg * 8 - 1)];
                    ami_win2(twA, dah01, myg, jj, c, A0, A1);
                }
            } else {
                int nW = (pcnt + 63) >> 6;
                for (int W = p; W < nW; W += 2) {
                    int wbase = W * 64;
                    int rem = pcnt - wbase;
                    int lim = min(rem, 64);
                    uint2 twA = tpay[pbeg + wbase + min(l, rem - 1)];
                    ami_win2(twA, dah01, lim >> 3, jj, c, A0, A1);
                }
            }
        }

        // reduce over jj within wave (lanes l, l^8, l^16, l^32)
#pragma unroll
        for (int msk = 8; msk <= 32; msk <<= 1) {
#pragma unroll
            for (int k = 0; k < 5; k++) {
                A0[k] += __shfl_xor(A0[k], msk, 64);
                A1[k] += __shfl_xor(A1[k], msk, 64);
            }
        }
        if (p == 1 && l < 8) {
#pragma unroll
            for (int k = 0; k < 5; k++) {
                sam[slot][k][l]     = A0[k];
                sam[slot][k + 5][l] = A1[k];
            }
        }
        __syncthreads();
        if (valid && p == 0 && l < 8) {
            unsigned short* o0 = &ao0[(size_t)i * astride0 + c];
            unsigned short* o1 = &ao1[(size_t)i * astride1 + c];
#pragma unroll
            for (int k = 0; k < 5; k++) {
                o0[k * 8] = f2bf_rn(A0[k] + sam[slot][k][l]);
                o1[k * 8] = f2bf_rn(A1[k] + sam[slot][k + 5][l]);
            }
        }
    } else {
        // ---------------- mi ----------------
        int i = ((int)blockIdx.x - amiCnt) * 2 + slot;
        bool valid = (i < N_ATOMS);
        int pbeg = 0, pcnt = 0;
        if (valid) { pbeg = ebase[i]; pcnt = epcnt[i]; }
        int n = l >> 3, cb = (l & 7) * 4;
        float4 acc = make_float4(0.f, 0.f, 0.f, 0.f);

        if (pcnt > 0) {
            int nG = pcnt >> 3;
            int h0 = (nG + 1) >> 1;
            int gbeg = p ? h0 : 0;
            int gend = p ? nG : h0;
            if (pcnt <= 64) {
                int eWin = edi[pbeg + min(l, pcnt - 1)];
                if (gbeg < gend) {
                    int cA = (int)erb[((size_t)pbeg + gbeg * 8) * 8 + l];
                    for (int g = gbeg; g < gend; g++) {
                        float4 v[8];
#pragma unroll
                        for (int j = 0; j < 8; j++) {
                            int eid = __shfl(eWin, g * 8 + j, 64);
                            v[j] = *(const float4*)&sd[eid * 32 + cb];
                        }
                        int cB = 0;
                        if (g + 1 < gend) cB = (int)erb[((size_t)pbeg + g * 8 + 8) * 8 + l];
#pragma unroll
                        for (int j = 0; j < 8; j++) {
                            float rbj = bf2f((unsigned short)__shfl(cA, j * 8 + n, 64));
                            acc.x += rbj * v[j].x; acc.y += rbj * v[j].y;
                            acc.z += rbj * v[j].z; acc.w += rbj * v[j].w;
                        }
                        if (g + 1 < gend) cA = cB;
                    }
                }
            } else {
                const int* dp = edi + pbeg;
                for (int g = gbeg; g < gend; g++) {
                    const unsigned short* rp = erb + ((size_t)pbeg + g * 8) * 8 + n;
                    float4 v[8];
#pragma unroll
                    for (int j = 0; j < 8; j++) {
                        int eid = dp[g * 8 + j];
                        v[j] = *(const float4*)&sd[eid * 32 + cb];
                    }
#pragma unroll
                    for (int j = 0; j < 8; j++) {
                        float rbj = bf2f(rp[j * 8]);
                        acc.x += rbj * v[j].x; acc.y += rbj * v[j].y;
                        acc.z += rbj * v[j].z; acc.w += rbj * v[j].w;
                    }
                }
            }
        }

        if (p == 1) smi[slot][l] = acc;
        __syncthreads();
        if (valid && p == 0) {
            float4 o = smi[slot][l];
            acc.x += o.x; acc.y += o.y; acc.z += o.z; acc.w += o.w;
            ushort4 pk = make_ushort4(f2bf_rn(acc.x), f2bf_rn(acc.y),
                                      f2bf_rn(acc.z), f2bf_rn(acc.w));
            *(ushort4*)&mo[(size_t)i * mstride + l * 4] = pk;   // n*32+cb == l*4
        }
    }
}

// ------------------------------------------------------------------
// MFMA GEMM: dxi = tssr2(ei @ W + b). ei bf16 (raw 8B A-staging).
// LAYER 0 writes bf16 ei1 (cols [0,256) only — ami1's [576,616)
// written earlier by k_seg survives); LAYER 1 writes fp32 out.
// ------------------------------------------------------------------
template <int LAYER>
__global__ __launch_bounds__(256) void k_gemm(const unsigned short* __restrict__ ei,
                                              const bf8* __restrict__ Wf,
                                              const float* __restrict__ bias,
                                              const unsigned short* __restrict__ skip,
                                              float* __restrict__ outf,
                                              unsigned short* __restrict__ outb) {
    constexpr int DINP = (LAYER == 0) ? DINP0 : DINP1;
    constexpr int NCH = DINP / 32;
    __shared__ __align__(16) __bf16 Asg[2][64][8];
    int t = threadIdx.x;
    int w = t >> 6, lane = t & 63;
    int a0 = blockIdx.x * 32;

    int f  = t * 4;
    int tA = f >> 9;
    int al = (f >> 3) & 63;
    int j0 = f & 7;
    int sm = al & 15, sq = al >> 4;
    int ga = a0 + tA * 16 + sm;
    const unsigned short* arow = &ei[(size_t)ga * DINP + sq * 8 + j0];
    __bf16* adst = &Asg[0][0][0] + f;
    bool aok = (ga < N_ATOMS);

    f4 acc[2][4];
#pragma unroll
    for (int i = 0; i < 2; i++)
#pragma unroll
        for (int j = 0; j < 4; j++) {
            f4 z = {0.f, 0.f, 0.f, 0.f};
            acc[i][j] = z;
        }

    for (int ch = 0; ch < NCH; ch++) {
        uint2 v = make_uint2(0, 0);
        if (aok) v = *(const uint2*)(arow + ch * 32);
        __syncthreads();
        *(uint2*)adst = v;
        __syncthreads();
        bf8 afr0 = *(const bf8*)&Asg[0][lane][0];
        bf8 afr1 = *(const bf8*)&Asg[1][lane][0];
        const bf8* wp = &Wf[(ch * 16 + w * 4) * 64 + lane];
#pragma unroll
        for (int tn = 0; tn < 4; tn++) {
            bf8 b = wp[tn * 64];
            acc[0][tn] = __builtin_amdgcn_mfma_f32_16x16x32_bf16(afr0, b, acc[0][tn], 0, 0, 0);
            acc[1][tn] = __builtin_amdgcn_mfma_f32_16x16x32_bf16(afr1, b, acc[1][tn], 0, 0, 0);
        }
    }

    int nlo = lane & 15, q = lane >> 4;
#pragma unroll
    for (int tA2 = 0; tA2 < 2; tA2++) {
#pragma unroll
        for (int r = 0; r < 4; r++) {
            int atom = a0 + tA2 * 16 + q * 4 + r;
            if (atom < N_ATOMS) {
#pragma unroll
                for (int tn = 0; tn < 4; tn++) {
                    int col = w * 64 + tn * 16 + nlo;
                    float vv = tssr2f(acc[tA2][tn][r] + bias[col]);
                    if (LAYER == 0) {
                        outb[(size_t)atom * DINP1 + col] = f2bf_rn(vv);
                    } else {
                        outf[(size_t)atom * 256 + col] =
                            vv + bf2f(skip[(size_t)atom * DINP1 + col]);
                    }
                }
            }
        }
    }
}

// ------------------------------------------------------------------
extern "C" void kernel_launch(void* const* d_in, const int* in_sizes, int n_in,
                              void* d_out, int out_size, void* d_ws, size_t ws_size,
                              hipStream_t stream) {
    const int*   species     = (const int*)d_in[0];
    const int*   edge_src    = (const int*)d_in[1];
    const int*   edge_dst    = (const int*)d_in[2];
    const float* distances   = (const float*)d_in[3];
    const float* sw          = (const float*)d_in[4];
    const float* angles      = (const float*)d_in[5];
    const int*   angle_src   = (const int*)d_in[6];
    const int*   angle_dst   = (const int*)d_in[7];
    const int*   central     = (const int*)d_in[8];
    const float* dist_a      = (const float*)d_in[9];
    const float* sw_a        = (const float*)d_in[10];
    const float* table       = (const float*)d_in[11];
    const float* W_si0       = (const float*)d_in[12];
    const float* W_si1       = (const float*)d_in[13];
    const float* W_da0       = (const float*)d_in[14];
    const float* W_da1       = (const float*)d_in[15];
    const float* W_mix0      = (const float*)d_in[16];
    const float* b_mix0      = (const float*)d_in[17];
    const float* W_mix1      = (const float*)d_in[18];
    const float* b_mix1      = (const float*)d_in[19];
    float* out = (float*)d_out;

    char* p = (char*)d_ws;
    auto alloc = [&](size_t bytes) {
        char* r = p;
        p += (bytes + 255) & ~(size_t)255;
        return (void*)r;
    };
    unsigned short* ei0 = (unsigned short*)alloc((size_t)N_ATOMS * DINP0 * 2);
    unsigned short* ei1 = (unsigned short*)alloc((size_t)N_ATOMS * DINP1 * 2);
    float*  sd   = (float*)alloc((size_t)N_ATOMS * 32 * 4);
    unsigned* dah01 = (unsigned*)alloc((size_t)(NEA + 1) * 8 * 4);
    unsigned short* erbf = (unsigned short*)alloc((size_t)(NE + NBUK * PADB) * 8 * 2);
    int*    edi  = (int*)alloc((size_t)(NE + NBUK * PADB) * 4);
    uint2*  tpay = (uint2*)alloc((size_t)(NT + NBUK * PADB) * 8);
    float4* ebuk = (float4*)alloc((size_t)NE * 16);
    bf8*    Wf0  = (bf8*)alloc((size_t)NFRAG0 * 16);
    bf8*    Wf1  = (bf8*)alloc((size_t)NFRAG1 * 16);
    bf8*    WfS1 = (bf8*)alloc((size_t)NFRAGS * 16);
    int* ebase  = (int*)alloc((size_t)N_ATOMS * 4);
    int* epcnt  = (int*)alloc((size_t)N_ATOMS * 4);
    int* tbase  = (int*)alloc((size_t)N_ATOMS * 4);
    int* tpcnt  = (int*)alloc((size_t)N_ATOMS * 4);
    int* bcnt   = (int*)alloc((size_t)2 * NBUK * 4);   // ebcnt | tbcnt (one memset)
    int* ebkoff = (int*)alloc((size_t)(NBUK + 1) * 4);
    int* tbkoff = (int*)alloc((size_t)(NBUK + 1) * 4);
    int* gce    = (int*)alloc((size_t)NBUK * 4);
    int* gct    = (int*)alloc((size_t)NBUK * 4);
    (void)ws_size;
    int* ebcnt = bcnt;
    int* tbcnt = bcnt + NBUK;

    // triplet staging aliases ei1 (consumed by k_binB2 before ei1 written;
    // k_seg L0's ami1 write to ei1+576 happens AFTER k_binB2)
    float4* tbuk = (float4*)ei1;

    hipMemsetAsync(bcnt, 0, (size_t)2 * NBUK * 4, stream);

    k_wc<<<WBLK + EBLK + TBLK, 256, 0, stream>>>(
        W_mix0, Wf0, W_mix1, Wf1, W_si1, WfS1,
        edge_src, central, ebcnt, tbcnt);

    k_scanB<<<2, 512, 0, stream>>>(ebcnt, ebkoff, gce, tbcnt, tbkoff, gct);

    k_bpre<<<EBLK + TBLK + S0BLK2 + DABLK2, 512, 0, stream>>>(
        distances, sw, edge_dst, edge_src, gce, ebuk,
        angles, angle_src, angle_dst, central, gct, tbuk,
        species, table, W_si0, ei0, sd,
        dist_a, sw_a, W_da0, W_da1, dah01);

    k_binB2<<<2 * NBUK, 256, 0, stream>>>(
        ebkoff, ebcnt, ebuk, erbf, edi, ebase, epcnt,
        tbkoff, tbcnt, tbuk, tpay, tbase, tpcnt);

    int gemm_grid = (N_ATOMS + 31) / 32;

    // ---- layer 0 (ami computes BOTH layers' angular term) ----
    k_seg<<<2 * MIBLK, 256, 0, stream>>>(ebase, epcnt, erbf, edi, sd, ei0 + 80, DINP0,
                                         tbase, tpcnt, tpay, dah01,
                                         ei0 + 336, DINP0, ei1 + 576, DINP1, MIBLK);
    k_gemm<0><<<gemm_grid, 256, 0, stream>>>(ei0, Wf0, b_mix0, nullptr, nullptr, ei1);

    // ---- layer 1 (mi only; ami1 already in ei1+576) ----
    k_s1<<<(N_ATOMS + 63) / 64, 256, 0, stream>>>(ei1, WfS1, ei1, sd);
    k_seg<<<MIBLK, 256, 0, stream>>>(ebase, epcnt, erbf, edi, sd, ei1 + 320, DINP1,
                                     tbase, tpcnt, tpay, dah01,
                                     ei1 + 576, DINP1, ei1 + 576, DINP1, 0);
    k_gemm<1><<<gemm_grid, 256, 0, stream>>>(ei1, Wf1, b_mix1, ei1, out, nullptr);
}